// Round 12
// baseline (3029.208 us; speedup 1.0000x reference)
//
#include <hip/hip_runtime.h>
#include <math.h>

// ---------------- problem constants ----------------
#define BATCH 16
#define L_CYC 20
#define CDL 128
#define SEQ 2560            // L_CYC * CDL
#define ENC_IN 3
#define DMODEL 512
#define DFF 2048
#define NLAYERS 2
#define TOPK 7
#define MROWS (BATCH*SEQ)   // 40960
#define SD ((size_t)BATCH * SEQ * DMODEL)   // 20,971,520
#define FFN_CHUNK 10240     // 10240*2048 == SD elements
#define CHUNK_D 256         // q/k column-chunk width
#define DGRP 4              // FFT channels per workgroup (1024 blocks -> 3/CU resident)

typedef short bf16x8 __attribute__((ext_vector_type(8)));
typedef float f32x4 __attribute__((ext_vector_type(4)));

__device__ __forceinline__ float gelu_f(float x) {
    return 0.5f * x * (1.0f + erff(x * 0.70710678118654752f));
}
__device__ __forceinline__ unsigned short f2bf(float f) {
    unsigned int u = __float_as_uint(f);
    u += 0x7fff + ((u >> 16) & 1);          // RNE
    return (unsigned short)(u >> 16);
}
__device__ __forceinline__ float bf2f(unsigned short h) {
    return __uint_as_float(((unsigned int)h) << 16);
}

// ---------------- embed: mask + reshape + circular conv1d(k=3) ----------------
__global__ __launch_bounds__(256) void embed_kernel(
    const float* __restrict__ data, const float* __restrict__ mask,
    const float* __restrict__ Wemb, float* __restrict__ h) {
    __shared__ float xv[9];     // [c*3 + t]
    size_t idx = (size_t)blockIdx.x * 256 + threadIdx.x;
    size_t r = idx >> 9;
    int s = (int)(r % SEQ);
    int b = (int)(r / SEQ);
    int tid = threadIdx.x;
    if (tid < 9) {
        int t = tid / 3, c = tid % 3;
        int u = s - 1 + t;
        if (u < 0) u += SEQ;
        if (u >= SEQ) u -= SEQ;
        int cyc = u >> 7, pos = u & 127;
        float mk = mask[b * L_CYC + cyc];
        xv[c * 3 + t] = (mk == 0.f) ? 0.f
            : data[(((size_t)b * L_CYC + cyc) * ENC_IN + c) * CDL + pos];
    }
    __syncthreads();
    int dm = idx & (DMODEL - 1);
    float acc = 0.f;
#pragma unroll
    for (int j = 0; j < 9; j++) acc += xv[j] * Wemb[dm * 9 + j];
    h[idx] = acc;
}

// ---------------- fp32 -> bf16 hi + lo (split precision) ----------------
__global__ void conv_split_kernel(const float* __restrict__ in,
                                  unsigned short* __restrict__ hi,
                                  unsigned short* __restrict__ lo, size_t n) {
    size_t i = ((size_t)blockIdx.x * 256 + threadIdx.x) * 4;
    if (i >= n) return;
    float4 v = *(const float4*)(in + i);
    float vv[4] = { v.x, v.y, v.z, v.w };
#pragma unroll
    for (int j = 0; j < 4; j++) {
        unsigned short h = f2bf(vv[j]);
        hi[i + j] = h;
        lo[i + j] = f2bf(vv[j] - bf2f(h));
    }
}

// ---------------- transpose W[K][N] fp32 -> Wt[N][K] bf16 ----------------
__global__ __launch_bounds__(256) void transpose_bf16_kernel(
    const float* __restrict__ W, unsigned short* __restrict__ Wt, int K, int N) {
    __shared__ float t[32][33];
    int n0 = blockIdx.x * 32, k0 = blockIdx.y * 32;
    int c = threadIdx.x & 31, r = threadIdx.x >> 5;   // r: 0..7
    for (int i = 0; i < 4; i++)
        t[r + i * 8][c] = W[(size_t)(k0 + r + i * 8) * N + n0 + c];
    __syncthreads();
    for (int i = 0; i < 4; i++)
        Wt[(size_t)(n0 + r + i * 8) * K + k0 + c] = f2bf(t[c][r + i * 8]);
}

// ---- transpose 512x512 W -> STACKED hi/lo bf16: q/k interleaved per 256-chunk ----
__global__ __launch_bounds__(256) void transpose_split_stk_kernel(
    const float* __restrict__ W, unsigned short* __restrict__ WtH,
    unsigned short* __restrict__ WtL, int which) {
    __shared__ float t[32][33];
    int n0 = blockIdx.x * 32, k0 = blockIdx.y * 32;
    int c = threadIdx.x & 31, r = threadIdx.x >> 5;
    for (int i = 0; i < 4; i++)
        t[r + i * 8][c] = W[(size_t)(k0 + r + i * 8) * DMODEL + n0 + c];
    __syncthreads();
    for (int i = 0; i < 4; i++) {
        int n = n0 + r + i * 8;
        int row = (n & 255) + ((n >> 8) * 512) + which * 256;
        float v = t[c][r + i * 8];
        unsigned short h = f2bf(v);
        size_t o = (size_t)row * DMODEL + k0 + c;
        WtH[o] = h;
        WtL[o] = f2bf(v - bf2f(h));
    }
}

// ---------------- stacked bias ----------------
__global__ void stack_bias_kernel(const float* __restrict__ bq,
                                  const float* __restrict__ bk, float* __restrict__ bstk) {
    int i = blockIdx.x * 256 + threadIdx.x;     // 0..1023
    if (i >= 1024) return;
    int c = i >> 9, j = i & 511;
    bstk[i] = (j < 256) ? bq[c * 256 + j] : bk[c * 256 + (j - 256)];
}

// ---------------- Wvo = Wv @ Wo (fp32, per layer; 512 blocks) ----------------
__global__ __launch_bounds__(256) void wvo_kernel(
    const float* __restrict__ Wv, const float* __restrict__ Wo,
    float* __restrict__ Wvo) {
    __shared__ float row[DMODEL];
    int k = blockIdx.x;
    int tid = threadIdx.x;
    for (int j = tid; j < DMODEL; j += 256) row[j] = Wv[(size_t)k * DMODEL + j];
    __syncthreads();
    float a0 = 0.f, a1 = 0.f;
    for (int j = 0; j < DMODEL; j++) {
        float wv = row[j];
        a0 += wv * Wo[(size_t)j * DMODEL + tid];
        a1 += wv * Wo[(size_t)j * DMODEL + tid + 256];
    }
    Wvo[(size_t)k * DMODEL + tid] = a0;
    Wvo[(size_t)k * DMODEL + tid + 256] = a1;
}

// ---------------- cb = bv @ Wo + bo ----------------
__global__ void cbias_kernel(const float* __restrict__ bv, const float* __restrict__ Wo,
                             const float* __restrict__ bo, float* __restrict__ cb) {
    int n = blockIdx.x * 256 + threadIdx.x;
    if (n >= DMODEL) return;
    float acc = bo[n];
    for (int j = 0; j < DMODEL; j++) acc += bv[j] * Wo[(size_t)j * DMODEL + n];
    cb[n] = acc;
}

// ---------------- bf16 MFMA GEMM (register staging, round-7 proven) ----------
#define BK 32
__global__ __launch_bounds__(256) void gemm_mfma_kernel(
    const unsigned short* __restrict__ A, const unsigned short* __restrict__ Wt,
    const float* __restrict__ bias, const float* __restrict__ res,
    void* __restrict__ Cout, int M, int N, int K, int act, int outMode)
{
    __shared__ unsigned short As[128 * 40];
    __shared__ unsigned short Bs[128 * 40];
    int tid = threadIdx.x;
    int wave = tid >> 6, lane = tid & 63;
    int wm = wave & 1, wn = wave >> 1;
    int bm = blockIdx.y * 128, bn = blockIdx.x * 128;

    int r0 = tid >> 2;              // 0..63
    int koff = (tid & 3) * 8;       // 0,8,16,24
    const unsigned short* Ag = A  + (size_t)(bm + r0) * K + koff;
    const unsigned short* Bg = Wt + (size_t)(bn + r0) * K + koff;

    f32x4 acc[4][4] = {};
    int frow = lane & 15, fk = (lane >> 4) * 8;

    for (int k0 = 0; k0 < K; k0 += BK) {
        bf16x8 a0 = *(const bf16x8*)(Ag + k0);
        bf16x8 a1 = *(const bf16x8*)(Ag + (size_t)64 * K + k0);
        bf16x8 b0 = *(const bf16x8*)(Bg + k0);
        bf16x8 b1 = *(const bf16x8*)(Bg + (size_t)64 * K + k0);
        __syncthreads();
        *(bf16x8*)&As[r0 * 40 + koff]        = a0;
        *(bf16x8*)&As[(r0 + 64) * 40 + koff] = a1;
        *(bf16x8*)&Bs[r0 * 40 + koff]        = b0;
        *(bf16x8*)&Bs[(r0 + 64) * 40 + koff] = b1;
        __syncthreads();
        bf16x8 af[4], bfv[4];
#pragma unroll
        for (int mi = 0; mi < 4; mi++)
            af[mi] = *(const bf16x8*)&As[(wm * 64 + mi * 16 + frow) * 40 + fk];
#pragma unroll
        for (int nj = 0; nj < 4; nj++)
            bfv[nj] = *(const bf16x8*)&Bs[(wn * 64 + nj * 16 + frow) * 40 + fk];
#pragma unroll
        for (int mi = 0; mi < 4; mi++)
#pragma unroll
            for (int nj = 0; nj < 4; nj++)
                acc[mi][nj] = __builtin_amdgcn_mfma_f32_16x16x32_bf16(
                    af[mi], bfv[nj], acc[mi][nj], 0, 0, 0);
    }

    int lrow = (lane >> 4) * 4, lcol = lane & 15;
#pragma unroll
    for (int mi = 0; mi < 4; mi++) {
        int row0 = bm + wm * 64 + mi * 16 + lrow;
#pragma unroll
        for (int nj = 0; nj < 4; nj++) {
            int col = bn + wn * 64 + nj * 16 + lcol;
            float bv = bias ? bias[col] : 0.f;
            f32x4 v = acc[mi][nj];
#pragma unroll
            for (int r = 0; r < 4; r++) {
                int row = row0 + r;
                float x = v[r] + bv;
                if (res) x += res[(size_t)row * N + col];
                if (act == 1) x = gelu_f(x);
                if (outMode == 0) ((float*)Cout)[(size_t)row * N + col] = x;
                else              ((unsigned short*)Cout)[(size_t)row * N + col] = f2bf(x);
            }
        }
    }
}

// ---------------- split-precision MFMA GEMM for q/k (fp32-accurate) ----------
// Output fp32 TRANSPOSED: Ct[col*M + row]. With stacked weights N=512 covers q&k.
__global__ __launch_bounds__(256) void gemm_qk_split_kernel(
    const unsigned short* __restrict__ Ahi, const unsigned short* __restrict__ Alo,
    const unsigned short* __restrict__ Whi, const unsigned short* __restrict__ Wlo,
    const float* __restrict__ bias, float* __restrict__ Ct, int M, int K)
{
    __shared__ unsigned short AsH[128 * 40];
    __shared__ unsigned short AsL[128 * 40];
    __shared__ unsigned short BsH[128 * 40];
    __shared__ unsigned short BsL[128 * 40];
    int tid = threadIdx.x;
    int wave = tid >> 6, lane = tid & 63;
    int wm = wave & 1, wn = wave >> 1;
    int bm = blockIdx.y * 128, bn = blockIdx.x * 128;

    int r0 = tid >> 2;
    int koff = (tid & 3) * 8;
    const unsigned short* AgH = Ahi + (size_t)(bm + r0) * K + koff;
    const unsigned short* AgL = Alo + (size_t)(bm + r0) * K + koff;
    const unsigned short* BgH = Whi + (size_t)(bn + r0) * K + koff;
    const unsigned short* BgL = Wlo + (size_t)(bn + r0) * K + koff;

    f32x4 acc[4][4] = {};
    int frow = lane & 15, fk = (lane >> 4) * 8;

    for (int k0 = 0; k0 < K; k0 += BK) {
        bf16x8 ah0 = *(const bf16x8*)(AgH + k0);
        bf16x8 ah1 = *(const bf16x8*)(AgH + (size_t)64 * K + k0);
        bf16x8 al0 = *(const bf16x8*)(AgL + k0);
        bf16x8 al1 = *(const bf16x8*)(AgL + (size_t)64 * K + k0);
        bf16x8 bh0 = *(const bf16x8*)(BgH + k0);
        bf16x8 bh1 = *(const bf16x8*)(BgH + (size_t)64 * K + k0);
        bf16x8 bl0 = *(const bf16x8*)(BgL + k0);
        bf16x8 bl1 = *(const bf16x8*)(BgL + (size_t)64 * K + k0);
        __syncthreads();
        *(bf16x8*)&AsH[r0 * 40 + koff]        = ah0;
        *(bf16x8*)&AsH[(r0 + 64) * 40 + koff] = ah1;
        *(bf16x8*)&AsL[r0 * 40 + koff]        = al0;
        *(bf16x8*)&AsL[(r0 + 64) * 40 + koff] = al1;
        *(bf16x8*)&BsH[r0 * 40 + koff]        = bh0;
        *(bf16x8*)&BsH[(r0 + 64) * 40 + koff] = bh1;
        *(bf16x8*)&BsL[r0 * 40 + koff]        = bl0;
        *(bf16x8*)&BsL[(r0 + 64) * 40 + koff] = bl1;
        __syncthreads();
        bf16x8 afh[4], afl[4], bfh[4], bfl[4];
#pragma unroll
        for (int mi = 0; mi < 4; mi++) {
            int o = (wm * 64 + mi * 16 + frow) * 40 + fk;
            afh[mi] = *(const bf16x8*)&AsH[o];
            afl[mi] = *(const bf16x8*)&AsL[o];
        }
#pragma unroll
        for (int nj = 0; nj < 4; nj++) {
            int o = (wn * 64 + nj * 16 + frow) * 40 + fk;
            bfh[nj] = *(const bf16x8*)&BsH[o];
            bfl[nj] = *(const bf16x8*)&BsL[o];
        }
#pragma unroll
        for (int mi = 0; mi < 4; mi++)
#pragma unroll
            for (int nj = 0; nj < 4; nj++) {
                acc[mi][nj] = __builtin_amdgcn_mfma_f32_16x16x32_bf16(
                    afh[mi], bfh[nj], acc[mi][nj], 0, 0, 0);
                acc[mi][nj] = __builtin_amdgcn_mfma_f32_16x16x32_bf16(
                    afh[mi], bfl[nj], acc[mi][nj], 0, 0, 0);
                acc[mi][nj] = __builtin_amdgcn_mfma_f32_16x16x32_bf16(
                    afl[mi], bfh[nj], acc[mi][nj], 0, 0, 0);
            }
    }

    int lrow = (lane >> 4) * 4, lcol = lane & 15;
#pragma unroll
    for (int mi = 0; mi < 4; mi++) {
        int row0 = bm + wm * 64 + mi * 16 + lrow;
#pragma unroll
        for (int nj = 0; nj < 4; nj++) {
            int col = bn + wn * 64 + nj * 16 + lcol;
            float bv = bias ? bias[col] : 0.f;
            f32x4 v = acc[mi][nj];
#pragma unroll
            for (int r = 0; r < 4; r++)
                Ct[(size_t)col * M + row0 + r] = v[r] + bv;
        }
    }
}

// ---------------- 2560-pt FFT (radix-5 + sincos twiddle + 9x radix-2 Stockham) --
// Round-7/10 proven config. w512[m] = exp(-2*pi*i*m/512), m in [0,256).
__device__ void fft2560(float2* bufA, float2* bufB, const float2* w512, int tid) {
    const float w5r[5] = { 1.f,  0.30901699437494742f, -0.80901699437494742f,
                          -0.80901699437494742f,  0.30901699437494742f };
    const float w5i[5] = { 0.f, -0.95105651629515357f, -0.58778525229247312f,
                           0.58778525229247312f,  0.95105651629515357f };
    __syncthreads();
    const float TWO_PI = 6.283185307179586f;
    for (int j = tid; j < SEQ; j += 256) {
        int k1 = j >> 9, n2 = j & 511;
        float ar = 0.f, ai = 0.f;
        for (int n1 = 0; n1 < 5; n1++) {
            int m = (n1 * k1) % 5;
            float2 x = bufA[n1 * 512 + n2];
            ar += x.x * w5r[m] - x.y * w5i[m];
            ai += x.x * w5i[m] + x.y * w5r[m];
        }
        float ang = -TWO_PI * (float)(n2 * k1) / 2560.0f;
        float sn, cs;
        sincosf(ang, &sn, &cs);
        bufB[j] = make_float2(ar * cs - ai * sn, ar * sn + ai * cs);
    }
    __syncthreads();
    float2* X = bufB;
    float2* Y = bufA;
    int n = 512, logs = 0;
    for (int st = 0; st < 9; st++) {
        int m = n >> 1;
        int s = 1 << logs;
        for (int t = tid; t < 1280; t += 256) {
            int sub = t >> 8;
            int r = t & 255;
            int p = r >> logs;
            int q = r & (s - 1);
            int base = sub << 9;
            float2 a = X[base + q + s * p];
            float2 b = X[base + q + s * (p + m)];
            float2 sum = make_float2(a.x + b.x, a.y + b.y);
            float2 dif = make_float2(a.x - b.x, a.y - b.y);
            float2 w = w512[p << logs];
            Y[base + q + s * (2 * p)]     = sum;
            Y[base + q + s * (2 * p + 1)] = make_float2(dif.x * w.x - dif.y * w.y,
                                                        dif.x * w.y + dif.y * w.x);
        }
        __syncthreads();
        float2* tmp = X; X = Y; Y = tmp;
        n >>= 1; logs++;
    }
    // result in bufA: bufA[k1*512 + k2] = DFT[k1 + 5*k2]
}

// one workgroup per (DGRP-channel group, b): packed z = q + i*k, register-accumulated
// P[f], one atomicAdd pair per freq at the end.
__global__ __launch_bounds__(256) void fft_fwd_kernel(
    const float* __restrict__ qt, const float* __restrict__ kt, float* __restrict__ Z)
{
    __shared__ float2 bufA[SEQ];
    __shared__ float2 bufB[SEQ];
    __shared__ float2 w512[256];
    int d0 = blockIdx.x * DGRP;
    int b = blockIdx.y;
    int tid = threadIdx.x;
    {
        float sn, cs;
        sincosf(-6.283185307179586f * (float)tid / 512.0f, &sn, &cs);
        w512[tid] = make_float2(cs, sn);
    }
    float accR[10], accI[10];
#pragma unroll
    for (int j = 0; j < 10; j++) { accR[j] = 0.f; accI[j] = 0.f; }

    for (int col = 0; col < DGRP; col++) {
        const float* qcol = qt + (size_t)(d0 + col) * MROWS + (size_t)b * SEQ;
        const float* kcol = kt + (size_t)(d0 + col) * MROWS + (size_t)b * SEQ;
        __syncthreads();    // previous epilogue finished reading bufA
        for (int i = tid; i < SEQ; i += 256)
            bufA[i] = make_float2(qcol[i], kcol[i]);
        fft2560(bufA, bufB, w512, tid);   // entry barrier makes writes visible
#pragma unroll
        for (int j = 0; j < 10; j++) {
            int f = tid + 256 * j;
            int fpos = (f % 5) * 512 + (f / 5);
            int g = f ? (SEQ - f) : 0;
            int gpos = (g % 5) * 512 + (g / 5);
            float2 Z1 = bufA[fpos], Z2 = bufA[gpos];
            accR[j] += 0.5f * (Z1.x * Z2.y + Z1.y * Z2.x);            // Im(Z1*Z2)/2
            accI[j] += 0.25f * ((Z1.x * Z1.x + Z1.y * Z1.y)
                              - (Z2.x * Z2.x + Z2.y * Z2.y));         // (|Z1|^2-|Z2|^2)/4
        }
    }
#pragma unroll
    for (int j = 0; j < 10; j++) {
        int f = tid + 256 * j;
        int fpos = (f % 5) * 512 + (f / 5);
        atomicAdd(&Z[((size_t)b * SEQ + fpos) * 2 + 0], accR[j]);
        atomicAdd(&Z[((size_t)b * SEQ + fpos) * 2 + 1], accI[j]);
    }
}

__global__ __launch_bounds__(256) void fft_inv_kernel(
    const float* __restrict__ Z, float* __restrict__ mc)
{
    __shared__ float2 bufA[SEQ];
    __shared__ float2 bufB[SEQ];
    __shared__ float2 w512[256];
    int b = blockIdx.x;
    int tid = threadIdx.x;
    {
        float sn, cs;
        sincosf(-6.283185307179586f * (float)tid / 512.0f, &sn, &cs);
        w512[tid] = make_float2(cs, sn);
    }
    for (int i = tid; i < SEQ; i += 256) {
        int k1 = i % 5, k2 = i / 5;
        float zr = Z[((size_t)b * SEQ + k1 * 512 + k2) * 2 + 0];
        float zi = Z[((size_t)b * SEQ + k1 * 512 + k2) * 2 + 1];
        bufA[i] = make_float2(zr, -zi);
    }
    fft2560(bufA, bufB, w512, tid);
    const float scale = 1.0f / (2560.0f * 512.0f);
    for (int j = tid; j < SEQ; j += 256) {
        int k1 = j >> 9, k2 = j & 511;
        mc[(size_t)b * SEQ + k1 + 5 * k2] = bufA[j].x * scale;
    }
}

// ---------------- top-7 + softmax per batch ----------------
__global__ __launch_bounds__(256) void topk_kernel(
    const float* __restrict__ mc, float* __restrict__ wts, int* __restrict__ dels)
{
    __shared__ float cv[SEQ];
    __shared__ float rv[256];
    __shared__ int   ri[256];
    __shared__ float topv[TOPK];
    __shared__ int   topi[TOPK];
    int b = blockIdx.x, tid = threadIdx.x;
    for (int i = tid; i < SEQ; i += 256) cv[i] = mc[(size_t)b * SEQ + i];
    __syncthreads();
    for (int it = 0; it < TOPK; it++) {
        float bv = -2e30f; int bi = 1 << 30;
        for (int i = tid; i < SEQ; i += 256) {
            float v = cv[i];
            if (v > bv || (v == bv && i < bi)) { bv = v; bi = i; }
        }
        rv[tid] = bv; ri[tid] = bi;
        __syncthreads();
        for (int off = 128; off > 0; off >>= 1) {
            if (tid < off) {
                float v2 = rv[tid + off]; int i2 = ri[tid + off];
                if (v2 > rv[tid] || (v2 == rv[tid] && i2 < ri[tid])) {
                    rv[tid] = v2; ri[tid] = i2;
                }
            }
            __syncthreads();
        }
        if (tid == 0) { topv[it] = rv[0]; topi[it] = ri[0]; cv[ri[0]] = -1e30f; }
        __syncthreads();
    }
    if (tid == 0) {
        float mx = topv[0];
        float e[TOPK], ssum = 0.f;
        for (int i = 0; i < TOPK; i++) { e[i] = expf(topv[i] - mx); ssum += e[i]; }
        for (int i = 0; i < TOPK; i++) {
            wts[b * TOPK + i] = e[i] / ssum;
            dels[b * TOPK + i] = topi[i];
        }
    }
}

// ---------------- fused delay aggregation + bias + residual ------------------
__global__ void agg_res_kernel(const float* __restrict__ u, const float* __restrict__ x,
                               const float* __restrict__ cb,
                               const float* __restrict__ wts, const int* __restrict__ dels,
                               float* __restrict__ x1) {
    size_t idx = (size_t)blockIdx.x * 256 + threadIdx.x;
    if (idx >= SD) return;
    int d = idx & (DMODEL - 1);
    size_t r = idx >> 9;
    int s = (int)(r % SEQ);
    int b = (int)(r / SEQ);
    float acc = cb[d] + x[idx];
    for (int i = 0; i < TOPK; i++) {
        int del = dels[b * TOPK + i];
        float w = wts[b * TOPK + i];
        int ss = s + del; if (ss >= SEQ) ss -= SEQ;
        acc += w * u[((size_t)b * SEQ + ss) * DMODEL + d];
    }
    x1[idx] = acc;
}

// ---------------- x - moving_avg(x) family ----------------
__device__ __forceinline__ float ma_val(const float* __restrict__ x, size_t idx) {
    int d = (int)(idx & (DMODEL - 1));
    size_t r = idx >> 9;
    int s = (int)(r % SEQ);
    int b = (int)(r / SEQ);
    float acc = 0.f;
    for (int j = -12; j <= 12; j++) {
        int ss = s + j;
        ss = ss < 0 ? 0 : (ss > SEQ - 1 ? SEQ - 1 : ss);
        acc += x[((size_t)b * SEQ + ss) * DMODEL + d];
    }
    return x[idx] - acc * (1.0f / 25.0f);
}
__global__ void ma_sub_kernel(const float* __restrict__ x, float* __restrict__ out) {
    size_t idx = (size_t)blockIdx.x * 256 + threadIdx.x;
    if (idx >= SD) return;
    out[idx] = ma_val(x, idx);
}
// fp32 + plain bf16 (feeds FFN input + residual)
__global__ void ma_sub_bf_kernel(const float* __restrict__ x, float* __restrict__ out,
                                 unsigned short* __restrict__ obf) {
    size_t idx = (size_t)blockIdx.x * 256 + threadIdx.x;
    if (idx >= SD) return;
    float v = ma_val(x, idx);
    out[idx] = v;
    obf[idx] = f2bf(v);
}
// fp32 + hi/lo split (prepares next layer's x)
__global__ void ma_sub_split_kernel(const float* __restrict__ x, float* __restrict__ out,
                                    unsigned short* __restrict__ hi,
                                    unsigned short* __restrict__ lo) {
    size_t idx = (size_t)blockIdx.x * 256 + threadIdx.x;
    if (idx >= SD) return;
    float v = ma_val(x, idx);
    out[idx] = v;
    unsigned short h = f2bf(v);
    hi[idx] = h;
    lo[idx] = f2bf(v - bf2f(h));
}

// ---------------- layernorm over last dim ----------------
__global__ __launch_bounds__(256) void ln_kernel(
    const float* __restrict__ x, const float* __restrict__ g,
    const float* __restrict__ be, float* __restrict__ xh)
{
    int row = blockIdx.x;
    int tid = threadIdx.x;
    __shared__ float red[256];
    const float* xr = x + (size_t)row * DMODEL;
    float v0 = xr[tid], v1 = xr[tid + 256];
    red[tid] = v0 + v1;
    __syncthreads();
    for (int off = 128; off > 0; off >>= 1) {
        if (tid < off) red[tid] += red[tid + off];
        __syncthreads();
    }
    float mu = red[0] / (float)DMODEL;
    __syncthreads();
    float d0 = v0 - mu, d1 = v1 - mu;
    red[tid] = d0 * d0 + d1 * d1;
    __syncthreads();
    for (int off = 128; off > 0; off >>= 1) {
        if (tid < off) red[tid] += red[tid + off];
        __syncthreads();
    }
    float inv = rsqrtf(red[0] / (float)DMODEL + 1e-5f);
    xh[(size_t)row * DMODEL + tid]       = d0 * inv * g[tid] + be[tid];
    xh[(size_t)row * DMODEL + tid + 256] = d1 * inv * g[tid + 256] + be[tid + 256];
}

__global__ void colmean_kernel(const float* __restrict__ xh, float* __restrict__ cm) {
    int idx = blockIdx.x * 256 + threadIdx.x;
    if (idx >= BATCH * DMODEL) return;
    int d = idx & (DMODEL - 1), b = idx >> 9;
    float acc = 0.f;
    for (int s = 0; s < SEQ; s++) acc += xh[((size_t)b * SEQ + s) * DMODEL + d];
    cm[idx] = acc / (float)SEQ;
}

__global__ __launch_bounds__(256) void final_kernel(
    const float* __restrict__ xh, const float* __restrict__ cm,
    const float* __restrict__ Wp, const float* __restrict__ bp,
    float* __restrict__ out)
{
    int b = blockIdx.y, chunk = blockIdx.x;
    int tid = threadIdx.x;
    const size_t per = (size_t)SEQ * DMODEL / 64;
    size_t start = (size_t)chunk * per;
    float acc = 0.f;
    for (size_t i = start + tid; i < start + per; i += 256) {
        int d = (int)(i & (DMODEL - 1));
        float v = xh[(size_t)b * SEQ * DMODEL + i] - cm[b * DMODEL + d];
        acc += gelu_f(v) * Wp[i];
    }
    __shared__ float red[256];
    red[tid] = acc;
    __syncthreads();
    for (int off = 128; off > 0; off >>= 1) {
        if (tid < off) red[tid] += red[tid + off];
        __syncthreads();
    }
    if (tid == 0) {
        atomicAdd(&out[b], red[0]);
        if (chunk == 0) atomicAdd(&out[b], bp[0]);
    }
}

// ---------------- orchestration ----------------
// Workspace (f32 units of SD): A x/x2/h | B: Hbf/Lbf (x hi/lo) -> FFN bufs | C:
// qtf/ktf fp32 -> u fp32 -> z fp32. Tail: stacked weights + Wvo/Wc1t/Wc2t +
// cb/bstk/Zb/MC/WT/DL/CM (~8 MB). Total ~260 MB (proven).
extern "C" void kernel_launch(void* const* d_in, const int* in_sizes, int n_in,
                              void* d_out, int out_size, void* d_ws, size_t ws_size,
                              hipStream_t stream) {
    const float* data  = (const float*)d_in[0];
    const float* mask  = (const float*)d_in[1];
    const float* Wemb  = (const float*)d_in[2];
    const float* Wq    = (const float*)d_in[3];
    const float* bq    = (const float*)d_in[4];
    const float* Wk    = (const float*)d_in[5];
    const float* bk    = (const float*)d_in[6];
    const float* Wv    = (const float*)d_in[7];
    const float* bv    = (const float*)d_in[8];
    const float* Wo    = (const float*)d_in[9];
    const float* bo    = (const float*)d_in[10];
    const float* Wc1   = (const float*)d_in[11];
    const float* Wc2   = (const float*)d_in[12];
    const float* gamma = (const float*)d_in[13];
    const float* beta  = (const float*)d_in[14];
    const float* Wp    = (const float*)d_in[15];
    const float* bp    = (const float*)d_in[16];
    float* out = (float*)d_out;

    float* A  = (float*)d_ws;
    float* Bp = A + SD;
    float* Cp = Bp + SD;
    unsigned short* Lbf = (unsigned short*)Bp;      // B lower half: x_lo / x2 bf16
    unsigned short* Hbf = Lbf + SD;                 // B upper half: x_hi / FFN gelu
    float* qtf = Cp;                                // fp32 q chunk (MROWS*256)
    float* ktf = Cp + (size_t)MROWS * CHUNK_D;      // fp32 k chunk (adjacent)

    unsigned short* WstkH = (unsigned short*)(Cp + SD);     // 2*512*512 stacked q/k hi
    unsigned short* WstkL = WstkH + 2 * DMODEL * DMODEL;    // stacked q/k lo
    unsigned short* Wvot  = WstkL + 2 * DMODEL * DMODEL;    // bf16 [N][K] of Wv@Wo
    unsigned short* Wc1t  = Wvot + DMODEL * DMODEL;         // [2048][512]
    unsigned short* Wc2t  = Wc1t + (size_t)DMODEL * DFF;    // [512][2048]
    float* WvoF = (float*)(Wc2t + (size_t)DMODEL * DFF);    // fp32 Wv@Wo (512x512)
    float* CB   = WvoF + (size_t)DMODEL * DMODEL;           // cb = bv@Wo + bo
    float* Bstk = CB + DMODEL;                              // stacked q/k bias (1024)
    float* Zb = Bstk + 1024;
    float* MC = Zb + (size_t)BATCH * SEQ * 2;
    float* WT = MC + (size_t)BATCH * SEQ;
    int*   DL = (int*)(WT + BATCH * TOPK);
    float* CM = (float*)(DL + BATCH * TOPK);

    const int NB  = (int)((SD + 255) / 256);
    const int NB4 = (int)((SD / 4 + 255) / 256);

    embed_kernel<<<NB, 256, 0, stream>>>(data, mask, Wemb, A);
    // x -> hi (Hbf) + lo (Lbf) for layer 0; later layers produced by ma_sub_split
    conv_split_kernel<<<NB4, 256, 0, stream>>>(A, Hbf, Lbf, SD);

    dim3 gSq(DMODEL / 128, MROWS / 128);        // (4, 320)
    dim3 gF1(DFF / 128, FFN_CHUNK / 128);       // (16, 80)
    dim3 gF2(DMODEL / 128, FFN_CHUNK / 128);    // (4, 80)

    for (int l = 0; l < NLAYERS; l++) {
        const float* wq = Wq + (size_t)l * DMODEL * DMODEL;
        const float* wk = Wk + (size_t)l * DMODEL * DMODEL;
        const float* wv = Wv + (size_t)l * DMODEL * DMODEL;
        const float* wo = Wo + (size_t)l * DMODEL * DMODEL;
        const float* bqL = bq + (size_t)l * DMODEL;
        const float* bkL = bk + (size_t)l * DMODEL;
        const float* bvL = bv + (size_t)l * DMODEL;
        const float* boL = bo + (size_t)l * DMODEL;
        const float* wc1 = Wc1 + (size_t)l * DMODEL * DFF;
        const float* wc2 = Wc2 + (size_t)l * DFF * DMODEL;

        dim3 gT(DMODEL / 32, DMODEL / 32);
        transpose_split_stk_kernel<<<gT, 256, 0, stream>>>(wq, WstkH, WstkL, 0);
        transpose_split_stk_kernel<<<gT, 256, 0, stream>>>(wk, WstkH, WstkL, 1);
        stack_bias_kernel<<<4, 256, 0, stream>>>(bqL, bkL, Bstk);
        wvo_kernel<<<DMODEL, 256, 0, stream>>>(wv, wo, WvoF);
        transpose_bf16_kernel<<<gT, 256, 0, stream>>>(WvoF, Wvot, DMODEL, DMODEL);
        cbias_kernel<<<2, 256, 0, stream>>>(bvL, wo, boL, CB);
        transpose_bf16_kernel<<<dim3(DFF / 32, DMODEL / 32), 256, 0, stream>>>(wc1, Wc1t, DMODEL, DFF);
        transpose_bf16_kernel<<<dim3(DMODEL / 32, DFF / 32), 256, 0, stream>>>(wc2, Wc2t, DFF, DMODEL);

        // q&k stacked: one split GEMM per 256-col chunk (N=512 covers both)
        hipMemsetAsync(Zb, 0, (size_t)BATCH * SEQ * 2 * sizeof(float), stream);
        for (int c = 0; c < DMODEL / CHUNK_D; c++) {
            gemm_qk_split_kernel<<<gSq, 256, 0, stream>>>(
                Hbf, Lbf, WstkH + (size_t)c * 512 * DMODEL,
                WstkL + (size_t)c * 512 * DMODEL, Bstk + c * 512,
                Cp, MROWS, DMODEL);
            fft_fwd_kernel<<<dim3(CHUNK_D / DGRP, BATCH), 256, 0, stream>>>(qtf, ktf, Zb);
        }
        fft_inv_kernel<<<BATCH, 256, 0, stream>>>(Zb, MC);
        topk_kernel<<<BATCH, 256, 0, stream>>>(MC, WT, DL);

        // u = x@(Wv@Wo) -> Cp fp32 (qtf/ktf dead)
        gemm_mfma_kernel<<<gSq, 256, 0, stream>>>(Hbf, Wvot, nullptr, nullptr, Cp,
                                                  MROWS, DMODEL, DMODEL, 0, 0);
        // x1 = sum w_i roll(u) + cb + x -> Bp fp32 (x_hi/x_lo dead)
        agg_res_kernel<<<NB, 256, 0, stream>>>(Cp, A, CB, WT, DL, Bp);
        // x2 = x1 - MA(x1) -> A fp32 + Lbf bf16 (fused; x dead)
        ma_sub_bf_kernel<<<NB, 256, 0, stream>>>(Bp, A, Lbf);
        // FFN in 4 row-chunks; gelu intermediate bf16 -> Hbf; z -> Cp (u dead)
        for (int c = 0; c < MROWS / FFN_CHUNK; c++) {
            const unsigned short* x2c = Lbf + (size_t)c * FFN_CHUNK * DMODEL;
            const float* resc = A + (size_t)c * FFN_CHUNK * DMODEL;
            float* zc = Cp + (size_t)c * FFN_CHUNK * DMODEL;
            gemm_mfma_kernel<<<gF1, 256, 0, stream>>>(x2c, Wc1t, nullptr, nullptr, Hbf,
                                                      FFN_CHUNK, DFF, DMODEL, 1, 1);
            gemm_mfma_kernel<<<gF2, 256, 0, stream>>>(Hbf, Wc2t, nullptr, resc, zc,
                                                      FFN_CHUNK, DMODEL, DFF, 0, 0);
        }
        // h = z - MA(z) -> A; if another layer follows also emit hi/lo (fused)
        if (l + 1 < NLAYERS)
            ma_sub_split_kernel<<<NB, 256, 0, stream>>>(Cp, A, Hbf, Lbf);
        else
            ma_sub_kernel<<<NB, 256, 0, stream>>>(Cp, A);
    }

    ln_kernel<<<MROWS, 256, 0, stream>>>(A, gamma, beta, Bp);
    colmean_kernel<<<(BATCH * DMODEL + 255) / 256, 256, 0, stream>>>(Bp, CM);
    hipMemsetAsync(out, 0, (size_t)out_size * sizeof(float), stream);
    final_kernel<<<dim3(64, BATCH), 256, 0, stream>>>(Bp, CM, Wp, bp, out);
}

// Round 14
// 2701.721 us; speedup vs baseline: 1.1212x; 1.1212x over previous
//
#include <hip/hip_runtime.h>
#include <math.h>

// ---------------- problem constants ----------------
#define BATCH 16
#define L_CYC 20
#define CDL 128
#define SEQ 2560            // L_CYC * CDL
#define ENC_IN 3
#define DMODEL 512
#define DFF 2048
#define NLAYERS 2
#define TOPK 7
#define MROWS (BATCH*SEQ)   // 40960
#define SD ((size_t)BATCH * SEQ * DMODEL)   // 20,971,520
#define FFN_CHUNK 10240     // 10240*2048 == SD elements
#define CHUNK_D 256         // q/k column-chunk width
#define DGRP 8              // FFT channels per workgroup (round-10 proven)

typedef short bf16x8 __attribute__((ext_vector_type(8)));
typedef float f32x4 __attribute__((ext_vector_type(4)));

__device__ __forceinline__ float gelu_f(float x) {
    return 0.5f * x * (1.0f + erff(x * 0.70710678118654752f));
}
__device__ __forceinline__ unsigned short f2bf(float f) {
    unsigned int u = __float_as_uint(f);
    u += 0x7fff + ((u >> 16) & 1);          // RNE
    return (unsigned short)(u >> 16);
}
__device__ __forceinline__ float bf2f(unsigned short h) {
    return __uint_as_float(((unsigned int)h) << 16);
}

// ---------------- embed: mask + reshape + circular conv1d(k=3) ----------------
__global__ __launch_bounds__(256) void embed_kernel(
    const float* __restrict__ data, const float* __restrict__ mask,
    const float* __restrict__ Wemb, float* __restrict__ h) {
    __shared__ float xv[9];     // [c*3 + t]
    size_t idx = (size_t)blockIdx.x * 256 + threadIdx.x;
    size_t r = idx >> 9;
    int s = (int)(r % SEQ);
    int b = (int)(r / SEQ);
    int tid = threadIdx.x;
    if (tid < 9) {
        int t = tid / 3, c = tid % 3;
        int u = s - 1 + t;
        if (u < 0) u += SEQ;
        if (u >= SEQ) u -= SEQ;
        int cyc = u >> 7, pos = u & 127;
        float mk = mask[b * L_CYC + cyc];
        xv[c * 3 + t] = (mk == 0.f) ? 0.f
            : data[(((size_t)b * L_CYC + cyc) * ENC_IN + c) * CDL + pos];
    }
    __syncthreads();
    int dm = idx & (DMODEL - 1);
    float acc = 0.f;
#pragma unroll
    for (int j = 0; j < 9; j++) acc += xv[j] * Wemb[dm * 9 + j];
    h[idx] = acc;
}

// ---------------- fp32 -> bf16 hi + lo (split precision) ----------------
__global__ void conv_split_kernel(const float* __restrict__ in,
                                  unsigned short* __restrict__ hi,
                                  unsigned short* __restrict__ lo, size_t n) {
    size_t i = ((size_t)blockIdx.x * 256 + threadIdx.x) * 4;
    if (i >= n) return;
    float4 v = *(const float4*)(in + i);
    float vv[4] = { v.x, v.y, v.z, v.w };
#pragma unroll
    for (int j = 0; j < 4; j++) {
        unsigned short h = f2bf(vv[j]);
        hi[i + j] = h;
        lo[i + j] = f2bf(vv[j] - bf2f(h));
    }
}

// ---------------- transpose W[K][N] fp32 -> Wt[N][K] bf16 ----------------
__global__ __launch_bounds__(256) void transpose_bf16_kernel(
    const float* __restrict__ W, unsigned short* __restrict__ Wt, int K, int N) {
    __shared__ float t[32][33];
    int n0 = blockIdx.x * 32, k0 = blockIdx.y * 32;
    int c = threadIdx.x & 31, r = threadIdx.x >> 5;   // r: 0..7
    for (int i = 0; i < 4; i++)
        t[r + i * 8][c] = W[(size_t)(k0 + r + i * 8) * N + n0 + c];
    __syncthreads();
    for (int i = 0; i < 4; i++)
        Wt[(size_t)(n0 + r + i * 8) * K + k0 + c] = f2bf(t[c][r + i * 8]);
}

// ---- transpose 512x512 W -> STACKED hi/lo bf16: q/k interleaved per 256-chunk ----
__global__ __launch_bounds__(256) void transpose_split_stk_kernel(
    const float* __restrict__ W, unsigned short* __restrict__ WtH,
    unsigned short* __restrict__ WtL, int which) {
    __shared__ float t[32][33];
    int n0 = blockIdx.x * 32, k0 = blockIdx.y * 32;
    int c = threadIdx.x & 31, r = threadIdx.x >> 5;
    for (int i = 0; i < 4; i++)
        t[r + i * 8][c] = W[(size_t)(k0 + r + i * 8) * DMODEL + n0 + c];
    __syncthreads();
    for (int i = 0; i < 4; i++) {
        int n = n0 + r + i * 8;
        int row = (n & 255) + ((n >> 8) * 512) + which * 256;
        float v = t[c][r + i * 8];
        unsigned short h = f2bf(v);
        size_t o = (size_t)row * DMODEL + k0 + c;
        WtH[o] = h;
        WtL[o] = f2bf(v - bf2f(h));
    }
}

// ---------------- stacked bias ----------------
__global__ void stack_bias_kernel(const float* __restrict__ bq,
                                  const float* __restrict__ bk, float* __restrict__ bstk) {
    int i = blockIdx.x * 256 + threadIdx.x;     // 0..1023
    if (i >= 1024) return;
    int c = i >> 9, j = i & 511;
    bstk[i] = (j < 256) ? bq[c * 256 + j] : bk[c * 256 + (j - 256)];
}

// ---------------- Wvo = Wv @ Wo (fp32, per layer; 512 blocks) ----------------
__global__ __launch_bounds__(256) void wvo_kernel(
    const float* __restrict__ Wv, const float* __restrict__ Wo,
    float* __restrict__ Wvo) {
    __shared__ float row[DMODEL];
    int k = blockIdx.x;
    int tid = threadIdx.x;
    for (int j = tid; j < DMODEL; j += 256) row[j] = Wv[(size_t)k * DMODEL + j];
    __syncthreads();
    float a0 = 0.f, a1 = 0.f;
    for (int j = 0; j < DMODEL; j++) {
        float wv = row[j];
        a0 += wv * Wo[(size_t)j * DMODEL + tid];
        a1 += wv * Wo[(size_t)j * DMODEL + tid + 256];
    }
    Wvo[(size_t)k * DMODEL + tid] = a0;
    Wvo[(size_t)k * DMODEL + tid + 256] = a1;
}

// ---------------- cb = bv @ Wo + bo ----------------
__global__ void cbias_kernel(const float* __restrict__ bv, const float* __restrict__ Wo,
                             const float* __restrict__ bo, float* __restrict__ cb) {
    int n = blockIdx.x * 256 + threadIdx.x;
    if (n >= DMODEL) return;
    float acc = bo[n];
    for (int j = 0; j < DMODEL; j++) acc += bv[j] * Wo[(size_t)j * DMODEL + n];
    cb[n] = acc;
}

// ---------------- bf16 MFMA GEMM (register staging, round-7 proven) ----------
// Note: res and Cout may legally alias at identical indices (in-place z = acc+res):
// each element is read and written by exactly one thread, read-before-write.
#define BK 32
__global__ __launch_bounds__(256) void gemm_mfma_kernel(
    const unsigned short* __restrict__ A, const unsigned short* __restrict__ Wt,
    const float* __restrict__ bias, const float* res,
    void* Cout, int M, int N, int K, int act, int outMode)
{
    __shared__ unsigned short As[128 * 40];
    __shared__ unsigned short Bs[128 * 40];
    int tid = threadIdx.x;
    int wave = tid >> 6, lane = tid & 63;
    int wm = wave & 1, wn = wave >> 1;
    int bm = blockIdx.y * 128, bn = blockIdx.x * 128;

    int r0 = tid >> 2;              // 0..63
    int koff = (tid & 3) * 8;       // 0,8,16,24
    const unsigned short* Ag = A  + (size_t)(bm + r0) * K + koff;
    const unsigned short* Bg = Wt + (size_t)(bn + r0) * K + koff;

    f32x4 acc[4][4] = {};
    int frow = lane & 15, fk = (lane >> 4) * 8;

    for (int k0 = 0; k0 < K; k0 += BK) {
        bf16x8 a0 = *(const bf16x8*)(Ag + k0);
        bf16x8 a1 = *(const bf16x8*)(Ag + (size_t)64 * K + k0);
        bf16x8 b0 = *(const bf16x8*)(Bg + k0);
        bf16x8 b1 = *(const bf16x8*)(Bg + (size_t)64 * K + k0);
        __syncthreads();
        *(bf16x8*)&As[r0 * 40 + koff]        = a0;
        *(bf16x8*)&As[(r0 + 64) * 40 + koff] = a1;
        *(bf16x8*)&Bs[r0 * 40 + koff]        = b0;
        *(bf16x8*)&Bs[(r0 + 64) * 40 + koff] = b1;
        __syncthreads();
        bf16x8 af[4], bfv[4];
#pragma unroll
        for (int mi = 0; mi < 4; mi++)
            af[mi] = *(const bf16x8*)&As[(wm * 64 + mi * 16 + frow) * 40 + fk];
#pragma unroll
        for (int nj = 0; nj < 4; nj++)
            bfv[nj] = *(const bf16x8*)&Bs[(wn * 64 + nj * 16 + frow) * 40 + fk];
#pragma unroll
        for (int mi = 0; mi < 4; mi++)
#pragma unroll
            for (int nj = 0; nj < 4; nj++)
                acc[mi][nj] = __builtin_amdgcn_mfma_f32_16x16x32_bf16(
                    af[mi], bfv[nj], acc[mi][nj], 0, 0, 0);
    }

    int lrow = (lane >> 4) * 4, lcol = lane & 15;
#pragma unroll
    for (int mi = 0; mi < 4; mi++) {
        int row0 = bm + wm * 64 + mi * 16 + lrow;
#pragma unroll
        for (int nj = 0; nj < 4; nj++) {
            int col = bn + wn * 64 + nj * 16 + lcol;
            float bv = bias ? bias[col] : 0.f;
            f32x4 v = acc[mi][nj];
#pragma unroll
            for (int r = 0; r < 4; r++) {
                int row = row0 + r;
                float x = v[r] + bv;
                if (res) x += res[(size_t)row * N + col];
                if (act == 1) x = gelu_f(x);
                if (outMode == 0) ((float*)Cout)[(size_t)row * N + col] = x;
                else              ((unsigned short*)Cout)[(size_t)row * N + col] = f2bf(x);
            }
        }
    }
}

// ---------------- split-precision MFMA GEMM for q/k (fp32-accurate) ----------
// Output fp32 TRANSPOSED: Ct[col*M + row]. With stacked weights N=512 covers q&k.
__global__ __launch_bounds__(256) void gemm_qk_split_kernel(
    const unsigned short* __restrict__ Ahi, const unsigned short* __restrict__ Alo,
    const unsigned short* __restrict__ Whi, const unsigned short* __restrict__ Wlo,
    const float* __restrict__ bias, float* __restrict__ Ct, int M, int K)
{
    __shared__ unsigned short AsH[128 * 40];
    __shared__ unsigned short AsL[128 * 40];
    __shared__ unsigned short BsH[128 * 40];
    __shared__ unsigned short BsL[128 * 40];
    int tid = threadIdx.x;
    int wave = tid >> 6, lane = tid & 63;
    int wm = wave & 1, wn = wave >> 1;
    int bm = blockIdx.y * 128, bn = blockIdx.x * 128;

    int r0 = tid >> 2;
    int koff = (tid & 3) * 8;
    const unsigned short* AgH = Ahi + (size_t)(bm + r0) * K + koff;
    const unsigned short* AgL = Alo + (size_t)(bm + r0) * K + koff;
    const unsigned short* BgH = Whi + (size_t)(bn + r0) * K + koff;
    const unsigned short* BgL = Wlo + (size_t)(bn + r0) * K + koff;

    f32x4 acc[4][4] = {};
    int frow = lane & 15, fk = (lane >> 4) * 8;

    for (int k0 = 0; k0 < K; k0 += BK) {
        bf16x8 ah0 = *(const bf16x8*)(AgH + k0);
        bf16x8 ah1 = *(const bf16x8*)(AgH + (size_t)64 * K + k0);
        bf16x8 al0 = *(const bf16x8*)(AgL + k0);
        bf16x8 al1 = *(const bf16x8*)(AgL + (size_t)64 * K + k0);
        bf16x8 bh0 = *(const bf16x8*)(BgH + k0);
        bf16x8 bh1 = *(const bf16x8*)(BgH + (size_t)64 * K + k0);
        bf16x8 bl0 = *(const bf16x8*)(BgL + k0);
        bf16x8 bl1 = *(const bf16x8*)(BgL + (size_t)64 * K + k0);
        __syncthreads();
        *(bf16x8*)&AsH[r0 * 40 + koff]        = ah0;
        *(bf16x8*)&AsH[(r0 + 64) * 40 + koff] = ah1;
        *(bf16x8*)&AsL[r0 * 40 + koff]        = al0;
        *(bf16x8*)&AsL[(r0 + 64) * 40 + koff] = al1;
        *(bf16x8*)&BsH[r0 * 40 + koff]        = bh0;
        *(bf16x8*)&BsH[(r0 + 64) * 40 + koff] = bh1;
        *(bf16x8*)&BsL[r0 * 40 + koff]        = bl0;
        *(bf16x8*)&BsL[(r0 + 64) * 40 + koff] = bl1;
        __syncthreads();
        bf16x8 afh[4], afl[4], bfh[4], bfl[4];
#pragma unroll
        for (int mi = 0; mi < 4; mi++) {
            int o = (wm * 64 + mi * 16 + frow) * 40 + fk;
            afh[mi] = *(const bf16x8*)&AsH[o];
            afl[mi] = *(const bf16x8*)&AsL[o];
        }
#pragma unroll
        for (int nj = 0; nj < 4; nj++) {
            int o = (wn * 64 + nj * 16 + frow) * 40 + fk;
            bfh[nj] = *(const bf16x8*)&BsH[o];
            bfl[nj] = *(const bf16x8*)&BsL[o];
        }
#pragma unroll
        for (int mi = 0; mi < 4; mi++)
#pragma unroll
            for (int nj = 0; nj < 4; nj++) {
                acc[mi][nj] = __builtin_amdgcn_mfma_f32_16x16x32_bf16(
                    afh[mi], bfh[nj], acc[mi][nj], 0, 0, 0);
                acc[mi][nj] = __builtin_amdgcn_mfma_f32_16x16x32_bf16(
                    afh[mi], bfl[nj], acc[mi][nj], 0, 0, 0);
                acc[mi][nj] = __builtin_amdgcn_mfma_f32_16x16x32_bf16(
                    afl[mi], bfh[nj], acc[mi][nj], 0, 0, 0);
            }
    }

    int lrow = (lane >> 4) * 4, lcol = lane & 15;
#pragma unroll
    for (int mi = 0; mi < 4; mi++) {
        int row0 = bm + wm * 64 + mi * 16 + lrow;
#pragma unroll
        for (int nj = 0; nj < 4; nj++) {
            int col = bn + wn * 64 + nj * 16 + lcol;
            float bv = bias ? bias[col] : 0.f;
            f32x4 v = acc[mi][nj];
#pragma unroll
            for (int r = 0; r < 4; r++)
                Ct[(size_t)col * M + row0 + r] = v[r] + bv;
        }
    }
}

// ---------------- 2560-pt FFT (radix-5 + sincos twiddle + 9x radix-2 Stockham) --
// Round-10 proven config. w512[m] = exp(-2*pi*i*m/512), m in [0,256).
__device__ void fft2560(float2* bufA, float2* bufB, const float2* w512, int tid) {
    const float w5r[5] = { 1.f,  0.30901699437494742f, -0.80901699437494742f,
                          -0.80901699437494742f,  0.30901699437494742f };
    const float w5i[5] = { 0.f, -0.95105651629515357f, -0.58778525229247312f,
                           0.58778525229247312f,  0.95105651629515357f };
    __syncthreads();
    const float TWO_PI = 6.283185307179586f;
    for (int j = tid; j < SEQ; j += 256) {
        int k1 = j >> 9, n2 = j & 511;
        float ar = 0.f, ai = 0.f;
        for (int n1 = 0; n1 < 5; n1++) {
            int m = (n1 * k1) % 5;
            float2 x = bufA[n1 * 512 + n2];
            ar += x.x * w5r[m] - x.y * w5i[m];
            ai += x.x * w5i[m] + x.y * w5r[m];
        }
        float ang = -TWO_PI * (float)(n2 * k1) / 2560.0f;
        float sn, cs;
        sincosf(ang, &sn, &cs);
        bufB[j] = make_float2(ar * cs - ai * sn, ar * sn + ai * cs);
    }
    __syncthreads();
    float2* X = bufB;
    float2* Y = bufA;
    int n = 512, logs = 0;
    for (int st = 0; st < 9; st++) {
        int m = n >> 1;
        int s = 1 << logs;
        for (int t = tid; t < 1280; t += 256) {
            int sub = t >> 8;
            int r = t & 255;
            int p = r >> logs;
            int q = r & (s - 1);
            int base = sub << 9;
            float2 a = X[base + q + s * p];
            float2 b = X[base + q + s * (p + m)];
            float2 sum = make_float2(a.x + b.x, a.y + b.y);
            float2 dif = make_float2(a.x - b.x, a.y - b.y);
            float2 w = w512[p << logs];
            Y[base + q + s * (2 * p)]     = sum;
            Y[base + q + s * (2 * p + 1)] = make_float2(dif.x * w.x - dif.y * w.y,
                                                        dif.x * w.y + dif.y * w.x);
        }
        __syncthreads();
        float2* tmp = X; X = Y; Y = tmp;
        n >>= 1; logs++;
    }
    // result in bufA: bufA[k1*512 + k2] = DFT[k1 + 5*k2]
}

// one workgroup per (DGRP-channel group, b): packed z = q + i*k, register-accumulated
// P[f], one atomicAdd pair per freq at the end.
__global__ __launch_bounds__(256) void fft_fwd_kernel(
    const float* __restrict__ qt, const float* __restrict__ kt, float* __restrict__ Z)
{
    __shared__ float2 bufA[SEQ];
    __shared__ float2 bufB[SEQ];
    __shared__ float2 w512[256];
    int d0 = blockIdx.x * DGRP;
    int b = blockIdx.y;
    int tid = threadIdx.x;
    {
        float sn, cs;
        sincosf(-6.283185307179586f * (float)tid / 512.0f, &sn, &cs);
        w512[tid] = make_float2(cs, sn);
    }
    float accR[10], accI[10];
#pragma unroll
    for (int j = 0; j < 10; j++) { accR[j] = 0.f; accI[j] = 0.f; }

    for (int col = 0; col < DGRP; col++) {
        const float* qcol = qt + (size_t)(d0 + col) * MROWS + (size_t)b * SEQ;
        const float* kcol = kt + (size_t)(d0 + col) * MROWS + (size_t)b * SEQ;
        __syncthreads();    // previous epilogue finished reading bufA
        for (int i = tid; i < SEQ; i += 256)
            bufA[i] = make_float2(qcol[i], kcol[i]);
        fft2560(bufA, bufB, w512, tid);   // entry barrier makes writes visible
#pragma unroll
        for (int j = 0; j < 10; j++) {
            int f = tid + 256 * j;
            int fpos = (f % 5) * 512 + (f / 5);
            int g = f ? (SEQ - f) : 0;
            int gpos = (g % 5) * 512 + (g / 5);
            float2 Z1 = bufA[fpos], Z2 = bufA[gpos];
            accR[j] += 0.5f * (Z1.x * Z2.y + Z1.y * Z2.x);            // Im(Z1*Z2)/2
            accI[j] += 0.25f * ((Z1.x * Z1.x + Z1.y * Z1.y)
                              - (Z2.x * Z2.x + Z2.y * Z2.y));         // (|Z1|^2-|Z2|^2)/4
        }
    }
#pragma unroll
    for (int j = 0; j < 10; j++) {
        int f = tid + 256 * j;
        int fpos = (f % 5) * 512 + (f / 5);
        atomicAdd(&Z[((size_t)b * SEQ + fpos) * 2 + 0], accR[j]);
        atomicAdd(&Z[((size_t)b * SEQ + fpos) * 2 + 1], accI[j]);
    }
}

__global__ __launch_bounds__(256) void fft_inv_kernel(
    const float* __restrict__ Z, float* __restrict__ mc)
{
    __shared__ float2 bufA[SEQ];
    __shared__ float2 bufB[SEQ];
    __shared__ float2 w512[256];
    int b = blockIdx.x;
    int tid = threadIdx.x;
    {
        float sn, cs;
        sincosf(-6.283185307179586f * (float)tid / 512.0f, &sn, &cs);
        w512[tid] = make_float2(cs, sn);
    }
    for (int i = tid; i < SEQ; i += 256) {
        int k1 = i % 5, k2 = i / 5;
        float zr = Z[((size_t)b * SEQ + k1 * 512 + k2) * 2 + 0];
        float zi = Z[((size_t)b * SEQ + k1 * 512 + k2) * 2 + 1];
        bufA[i] = make_float2(zr, -zi);
    }
    fft2560(bufA, bufB, w512, tid);
    const float scale = 1.0f / (2560.0f * 512.0f);
    for (int j = tid; j < SEQ; j += 256) {
        int k1 = j >> 9, k2 = j & 511;
        mc[(size_t)b * SEQ + k1 + 5 * k2] = bufA[j].x * scale;
    }
}

// ---------------- top-7 + softmax per batch ----------------
__global__ __launch_bounds__(256) void topk_kernel(
    const float* __restrict__ mc, float* __restrict__ wts, int* __restrict__ dels)
{
    __shared__ float cv[SEQ];
    __shared__ float rv[256];
    __shared__ int   ri[256];
    __shared__ float topv[TOPK];
    __shared__ int   topi[TOPK];
    int b = blockIdx.x, tid = threadIdx.x;
    for (int i = tid; i < SEQ; i += 256) cv[i] = mc[(size_t)b * SEQ + i];
    __syncthreads();
    for (int it = 0; it < TOPK; it++) {
        float bv = -2e30f; int bi = 1 << 30;
        for (int i = tid; i < SEQ; i += 256) {
            float v = cv[i];
            if (v > bv || (v == bv && i < bi)) { bv = v; bi = i; }
        }
        rv[tid] = bv; ri[tid] = bi;
        __syncthreads();
        for (int off = 128; off > 0; off >>= 1) {
            if (tid < off) {
                float v2 = rv[tid + off]; int i2 = ri[tid + off];
                if (v2 > rv[tid] || (v2 == rv[tid] && i2 < ri[tid])) {
                    rv[tid] = v2; ri[tid] = i2;
                }
            }
            __syncthreads();
        }
        if (tid == 0) { topv[it] = rv[0]; topi[it] = ri[0]; cv[ri[0]] = -1e30f; }
        __syncthreads();
    }
    if (tid == 0) {
        float mx = topv[0];
        float e[TOPK], ssum = 0.f;
        for (int i = 0; i < TOPK; i++) { e[i] = expf(topv[i] - mx); ssum += e[i]; }
        for (int i = 0; i < TOPK; i++) {
            wts[b * TOPK + i] = e[i] / ssum;
            dels[b * TOPK + i] = topi[i];
        }
    }
}

// ---------------- fused delay aggregation + bias + residual ------------------
__global__ void agg_res_kernel(const float* __restrict__ u, const float* __restrict__ x,
                               const float* __restrict__ cb,
                               const float* __restrict__ wts, const int* __restrict__ dels,
                               float* __restrict__ x1) {
    size_t idx = (size_t)blockIdx.x * 256 + threadIdx.x;
    if (idx >= SD) return;
    int d = idx & (DMODEL - 1);
    size_t r = idx >> 9;
    int s = (int)(r % SEQ);
    int b = (int)(r / SEQ);
    float acc = cb[d] + x[idx];
    for (int i = 0; i < TOPK; i++) {
        int del = dels[b * TOPK + i];
        float w = wts[b * TOPK + i];
        int ss = s + del; if (ss >= SEQ) ss -= SEQ;
        acc += w * u[((size_t)b * SEQ + ss) * DMODEL + d];
    }
    x1[idx] = acc;
}

// ---------------- x - moving_avg(x): running-window (3 reads/elem vs 25) -----
// grid (20, 2, 16): s-seg 128, d-half 256, b. NOTE: out/o1/o2 must NOT alias x.
#define MA_MODE_PLAIN 0
#define MA_MODE_BF    1
#define MA_MODE_SPLIT 2
template<int MODE>
__device__ __forceinline__ void ma_run_body(
    const float* __restrict__ x, float* __restrict__ out,
    unsigned short* __restrict__ o1, unsigned short* __restrict__ o2)
{
    int tid = threadIdx.x;
    int s0 = blockIdx.x * 128;
    int d  = blockIdx.y * 256 + tid;
    int b  = blockIdx.z;
    const float* xb = x + (size_t)b * SEQ * DMODEL + d;
    float sum = 0.f;
#pragma unroll
    for (int j = -12; j <= 12; j++) {
        int ss = s0 + j;
        ss = ss < 0 ? 0 : (ss > SEQ - 1 ? SEQ - 1 : ss);
        sum += xb[(size_t)ss * DMODEL];
    }
    for (int s = s0; s < s0 + 128; s++) {
        float v = xb[(size_t)s * DMODEL] - sum * (1.0f / 25.0f);
        size_t o = ((size_t)b * SEQ + s) * DMODEL + d;
        out[o] = v;
        if (MODE == MA_MODE_BF) {
            o1[o] = f2bf(v);
        } else if (MODE == MA_MODE_SPLIT) {
            unsigned short h = f2bf(v);
            o1[o] = h;
            o2[o] = f2bf(v - bf2f(h));
        }
        int add = s + 13; if (add > SEQ - 1) add = SEQ - 1;
        int sub = s - 12; if (sub < 0) sub = 0;
        sum += xb[(size_t)add * DMODEL] - xb[(size_t)sub * DMODEL];
    }
}
__global__ __launch_bounds__(256) void ma_sub_kernel(
    const float* __restrict__ x, float* __restrict__ out) {
    ma_run_body<MA_MODE_PLAIN>(x, out, nullptr, nullptr);
}
__global__ __launch_bounds__(256) void ma_sub_bf_kernel(
    const float* __restrict__ x, float* __restrict__ out,
    unsigned short* __restrict__ obf) {
    ma_run_body<MA_MODE_BF>(x, out, obf, nullptr);
}
__global__ __launch_bounds__(256) void ma_sub_split_kernel(
    const float* __restrict__ x, float* __restrict__ out,
    unsigned short* __restrict__ hi, unsigned short* __restrict__ lo) {
    ma_run_body<MA_MODE_SPLIT>(x, out, hi, lo);
}

// ---------------- layernorm over last dim ----------------
__global__ __launch_bounds__(256) void ln_kernel(
    const float* __restrict__ x, const float* __restrict__ g,
    const float* __restrict__ be, float* __restrict__ xh)
{
    int row = blockIdx.x;
    int tid = threadIdx.x;
    __shared__ float red[256];
    const float* xr = x + (size_t)row * DMODEL;
    float v0 = xr[tid], v1 = xr[tid + 256];
    red[tid] = v0 + v1;
    __syncthreads();
    for (int off = 128; off > 0; off >>= 1) {
        if (tid < off) red[tid] += red[tid + off];
        __syncthreads();
    }
    float mu = red[0] / (float)DMODEL;
    __syncthreads();
    float d0 = v0 - mu, d1 = v1 - mu;
    red[tid] = d0 * d0 + d1 * d1;
    __syncthreads();
    for (int off = 128; off > 0; off >>= 1) {
        if (tid < off) red[tid] += red[tid + off];
        __syncthreads();
    }
    float inv = rsqrtf(red[0] / (float)DMODEL + 1e-5f);
    xh[(size_t)row * DMODEL + tid]       = d0 * inv * g[tid] + be[tid];
    xh[(size_t)row * DMODEL + tid + 256] = d1 * inv * g[tid + 256] + be[tid + 256];
}

// ---------------- per-(b,d) mean over sequence (parallel, atomic partials) ----
__global__ __launch_bounds__(256) void colmean_kernel(
    const float* __restrict__ xh, float* __restrict__ cm) {
    int idx = blockIdx.x * 256 + threadIdx.x;   // (b,d) 0..8191
    int d = idx & (DMODEL - 1), b = idx >> 9;
    int s0 = blockIdx.y * 128;
    float acc = 0.f;
    for (int s = s0; s < s0 + 128; s++)
        acc += xh[((size_t)b * SEQ + s) * DMODEL + d];
    atomicAdd(&cm[idx], acc * (1.0f / (float)SEQ));
}

__global__ __launch_bounds__(256) void final_kernel(
    const float* __restrict__ xh, const float* __restrict__ cm,
    const float* __restrict__ Wp, const float* __restrict__ bp,
    float* __restrict__ out)
{
    int b = blockIdx.y, chunk = blockIdx.x;
    int tid = threadIdx.x;
    const size_t per = (size_t)SEQ * DMODEL / 64;
    size_t start = (size_t)chunk * per;
    float acc = 0.f;
    for (size_t i = start + tid; i < start + per; i += 256) {
        int d = (int)(i & (DMODEL - 1));
        float v = xh[(size_t)b * SEQ * DMODEL + i] - cm[b * DMODEL + d];
        acc += gelu_f(v) * Wp[i];
    }
    __shared__ float red[256];
    red[tid] = acc;
    __syncthreads();
    for (int off = 128; off > 0; off >>= 1) {
        if (tid < off) red[tid] += red[tid + off];
        __syncthreads();
    }
    if (tid == 0) {
        atomicAdd(&out[b], red[0]);
        if (chunk == 0) atomicAdd(&out[b], bp[0]);
    }
}

// ---------------- orchestration: 3-buffer rotation, NO input/output aliasing ----
// Per layer: X = x fp32 | HL = x hi/lo (-> x1 fp32 -> gelu bf16) | S = qtf/ktf
// -> u -> x2 bf16 -> h out. X and S swap each layer.
extern "C" void kernel_launch(void* const* d_in, const int* in_sizes, int n_in,
                              void* d_out, int out_size, void* d_ws, size_t ws_size,
                              hipStream_t stream) {
    const float* data  = (const float*)d_in[0];
    const float* mask  = (const float*)d_in[1];
    const float* Wemb  = (const float*)d_in[2];
    const float* Wq    = (const float*)d_in[3];
    const float* bq    = (const float*)d_in[4];
    const float* Wk    = (const float*)d_in[5];
    const float* bk    = (const float*)d_in[6];
    const float* Wv    = (const float*)d_in[7];
    const float* bv    = (const float*)d_in[8];
    const float* Wo    = (const float*)d_in[9];
    const float* bo    = (const float*)d_in[10];
    const float* Wc1   = (const float*)d_in[11];
    const float* Wc2   = (const float*)d_in[12];
    const float* gamma = (const float*)d_in[13];
    const float* beta  = (const float*)d_in[14];
    const float* Wp    = (const float*)d_in[15];
    const float* bp    = (const float*)d_in[16];
    float* out = (float*)d_out;

    float* buf0 = (float*)d_ws;
    float* buf1 = buf0 + SD;
    float* buf2 = buf1 + SD;

    unsigned short* WstkH = (unsigned short*)(buf2 + SD);   // 2*512*512 stacked q/k hi
    unsigned short* WstkL = WstkH + 2 * DMODEL * DMODEL;    // stacked q/k lo
    unsigned short* Wvot  = WstkL + 2 * DMODEL * DMODEL;    // bf16 [N][K] of Wv@Wo
    unsigned short* Wc1t  = Wvot + DMODEL * DMODEL;         // [2048][512]
    unsigned short* Wc2t  = Wc1t + (size_t)DMODEL * DFF;    // [512][2048]
    float* WvoF = (float*)(Wc2t + (size_t)DMODEL * DFF);    // fp32 Wv@Wo (512x512)
    float* CB   = WvoF + (size_t)DMODEL * DMODEL;           // cb = bv@Wo + bo
    float* Bstk = CB + DMODEL;                              // stacked q/k bias (1024)
    float* Zb = Bstk + 1024;
    float* MC = Zb + (size_t)BATCH * SEQ * 2;
    float* WT = MC + (size_t)BATCH * SEQ;
    int*   DL = (int*)(WT + BATCH * TOPK);
    float* CM = (float*)(DL + BATCH * TOPK);

    const int NB  = (int)((SD + 255) / 256);
    const int NB4 = (int)((SD / 4 + 255) / 256);
    dim3 gMA(SEQ / 128, 2, BATCH);              // (20, 2, 16) running-window MA

    float* X  = buf0;   // x fp32
    float* HL = buf1;   // hi/lo pool
    float* S  = buf2;   // scratch

    embed_kernel<<<NB, 256, 0, stream>>>(data, mask, Wemb, X);
    conv_split_kernel<<<NB4, 256, 0, stream>>>(
        X, (unsigned short*)HL + SD, (unsigned short*)HL, SD);  // hi -> upper, lo -> lower

    dim3 gSq(DMODEL / 128, MROWS / 128);        // (4, 320)
    dim3 gF1(DFF / 128, FFN_CHUNK / 128);       // (16, 80)
    dim3 gF2(DMODEL / 128, FFN_CHUNK / 128);    // (4, 80)

    for (int l = 0; l < NLAYERS; l++) {
        const float* wq = Wq + (size_t)l * DMODEL * DMODEL;
        const float* wk = Wk + (size_t)l * DMODEL * DMODEL;
        const float* wv = Wv + (size_t)l * DMODEL * DMODEL;
        const float* wo = Wo + (size_t)l * DMODEL * DMODEL;
        const float* bqL = bq + (size_t)l * DMODEL;
        const float* bkL = bk + (size_t)l * DMODEL;
        const float* bvL = bv + (size_t)l * DMODEL;
        const float* boL = bo + (size_t)l * DMODEL;
        const float* wc1 = Wc1 + (size_t)l * DMODEL * DFF;
        const float* wc2 = Wc2 + (size_t)l * DFF * DMODEL;

        unsigned short* Lbf = (unsigned short*)HL;      // x_lo (lower half)
        unsigned short* Hbf = Lbf + SD;                 // x_hi (upper half)
        float* qtf = S;                                 // q cols (MROWS*256)
        float* ktf = S + (size_t)MROWS * CHUNK_D;       // k cols

        dim3 gT(DMODEL / 32, DMODEL / 32);
        transpose_split_stk_kernel<<<gT, 256, 0, stream>>>(wq, WstkH, WstkL, 0);
        transpose_split_stk_kernel<<<gT, 256, 0, stream>>>(wk, WstkH, WstkL, 1);
        stack_bias_kernel<<<4, 256, 0, stream>>>(bqL, bkL, Bstk);
        wvo_kernel<<<DMODEL, 256, 0, stream>>>(wv, wo, WvoF);
        transpose_bf16_kernel<<<gT, 256, 0, stream>>>(WvoF, Wvot, DMODEL, DMODEL);
        cbias_kernel<<<2, 256, 0, stream>>>(bvL, wo, boL, CB);
        transpose_bf16_kernel<<<dim3(DFF / 32, DMODEL / 32), 256, 0, stream>>>(wc1, Wc1t, DMODEL, DFF);
        transpose_bf16_kernel<<<dim3(DMODEL / 32, DFF / 32), 256, 0, stream>>>(wc2, Wc2t, DFF, DMODEL);

        // q&k stacked: one split GEMM per 256-col chunk into S (N=512 covers both)
        hipMemsetAsync(Zb, 0, (size_t)BATCH * SEQ * 2 * sizeof(float), stream);
        for (int c = 0; c < DMODEL / CHUNK_D; c++) {
            gemm_qk_split_kernel<<<gSq, 256, 0, stream>>>(
                Hbf, Lbf, WstkH + (size_t)c * 512 * DMODEL,
                WstkL + (size_t)c * 512 * DMODEL, Bstk + c * 512,
                S, MROWS, DMODEL);
            fft_fwd_kernel<<<dim3(CHUNK_D / DGRP, BATCH), 256, 0, stream>>>(qtf, ktf, Zb);
        }
        fft_inv_kernel<<<BATCH, 256, 0, stream>>>(Zb, MC);
        topk_kernel<<<BATCH, 256, 0, stream>>>(MC, WT, DL);

        // u = x@(Wv@Wo) -> S fp32 (qtf/ktf dead)
        gemm_mfma_kernel<<<gSq, 256, 0, stream>>>(Hbf, Wvot, nullptr, nullptr, S,
                                                  MROWS, DMODEL, DMODEL, 0, 0);
        // x1 = sum w_i roll(u) + cb + x -> HL as fp32 (x hi/lo dead)
        agg_res_kernel<<<NB, 256, 0, stream>>>(S, X, CB, WT, DL, HL);
        // x2 = x1 - MA(x1): fp32 -> X (x dead), bf16 -> S (u dead). No aliasing.
        ma_sub_bf_kernel<<<gMA, 256, 0, stream>>>(HL, X, (unsigned short*)S);
        // FFN: gelu bf16 -> HL (x1 dead); z in-place over X (res==out, same-index)
        for (int c = 0; c < MROWS / FFN_CHUNK; c++) {
            const unsigned short* x2c = (unsigned short*)S + (size_t)c * FFN_CHUNK * DMODEL;
            float* xz = X + (size_t)c * FFN_CHUNK * DMODEL;
            gemm_mfma_kernel<<<gF1, 256, 0, stream>>>(x2c, Wc1t, nullptr, nullptr,
                                                      (unsigned short*)HL,
                                                      FFN_CHUNK, DFF, DMODEL, 1, 1);
            gemm_mfma_kernel<<<gF2, 256, 0, stream>>>((unsigned short*)HL, Wc2t,
                                                      nullptr, xz, xz,
                                                      FFN_CHUNK, DMODEL, DFF, 0, 0);
        }
        // h = z - MA(z): z in X -> h fp32 -> S (+ hi/lo -> HL if another layer)
        if (l + 1 < NLAYERS)
            ma_sub_split_kernel<<<gMA, 256, 0, stream>>>(
                X, S, (unsigned short*)HL + SD, (unsigned short*)HL);
        else
            ma_sub_kernel<<<gMA, 256, 0, stream>>>(X, S);
        // rotate: next layer's x is in S
        float* tmp = X; X = S; S = tmp;
    }

    // final h is in X; use HL for xh
    ln_kernel<<<MROWS, 256, 0, stream>>>(X, gamma, beta, HL);
    hipMemsetAsync(CM, 0, (size_t)BATCH * DMODEL * sizeof(float), stream);
    colmean_kernel<<<dim3(32, 20), 256, 0, stream>>>(HL, CM);
    hipMemsetAsync(out, 0, (size_t)out_size * sizeof(float), stream);
    final_kernel<<<dim3(64, BATCH), 256, 0, stream>>>(HL, CM, Wp, bp, out);
}

// Round 15
// 2400.434 us; speedup vs baseline: 1.2619x; 1.1255x over previous
//
#include <hip/hip_runtime.h>
#include <math.h>

// ---------------- problem constants ----------------
#define BATCH 16
#define L_CYC 20
#define CDL 128
#define SEQ 2560            // L_CYC * CDL
#define ENC_IN 3
#define DMODEL 512
#define DFF 2048
#define NLAYERS 2
#define TOPK 7
#define MROWS (BATCH*SEQ)   // 40960
#define SD ((size_t)BATCH * SEQ * DMODEL)   // 20,971,520
#define FFN_CHUNK 20480     // 2 chunks; 20480*2048 ushorts == SD*4 bytes exactly
#define CHUNK_D 256         // q/k column-chunk width
#define DGRP 8              // FFT channels per workgroup (proven)
#define FFT_NT 512          // threads per FFT block (this round's change)

typedef short bf16x8 __attribute__((ext_vector_type(8)));
typedef float f32x4 __attribute__((ext_vector_type(4)));

__device__ __forceinline__ float gelu_f(float x) {
    return 0.5f * x * (1.0f + erff(x * 0.70710678118654752f));
}
__device__ __forceinline__ unsigned short f2bf(float f) {
    unsigned int u = __float_as_uint(f);
    u += 0x7fff + ((u >> 16) & 1);          // RNE
    return (unsigned short)(u >> 16);
}
__device__ __forceinline__ float bf2f(unsigned short h) {
    return __uint_as_float(((unsigned int)h) << 16);
}

// ---------------- embed: mask + reshape + circular conv1d(k=3) ----------------
__global__ __launch_bounds__(256) void embed_kernel(
    const float* __restrict__ data, const float* __restrict__ mask,
    const float* __restrict__ Wemb, float* __restrict__ h) {
    __shared__ float xv[9];     // [c*3 + t]
    size_t idx = (size_t)blockIdx.x * 256 + threadIdx.x;
    size_t r = idx >> 9;
    int s = (int)(r % SEQ);
    int b = (int)(r / SEQ);
    int tid = threadIdx.x;
    if (tid < 9) {
        int t = tid / 3, c = tid % 3;
        int u = s - 1 + t;
        if (u < 0) u += SEQ;
        if (u >= SEQ) u -= SEQ;
        int cyc = u >> 7, pos = u & 127;
        float mk = mask[b * L_CYC + cyc];
        xv[c * 3 + t] = (mk == 0.f) ? 0.f
            : data[(((size_t)b * L_CYC + cyc) * ENC_IN + c) * CDL + pos];
    }
    __syncthreads();
    int dm = idx & (DMODEL - 1);
    float acc = 0.f;
#pragma unroll
    for (int j = 0; j < 9; j++) acc += xv[j] * Wemb[dm * 9 + j];
    h[idx] = acc;
}

// ---------------- fp32 -> bf16 hi + lo (split precision) ----------------
__global__ void conv_split_kernel(const float* __restrict__ in,
                                  unsigned short* __restrict__ hi,
                                  unsigned short* __restrict__ lo, size_t n) {
    size_t i = ((size_t)blockIdx.x * 256 + threadIdx.x) * 4;
    if (i >= n) return;
    float4 v = *(const float4*)(in + i);
    float vv[4] = { v.x, v.y, v.z, v.w };
#pragma unroll
    for (int j = 0; j < 4; j++) {
        unsigned short h = f2bf(vv[j]);
        hi[i + j] = h;
        lo[i + j] = f2bf(vv[j] - bf2f(h));
    }
}

// ---------------- transpose W[K][N] fp32 -> Wt[N][K] bf16 ----------------
__global__ __launch_bounds__(256) void transpose_bf16_kernel(
    const float* __restrict__ W, unsigned short* __restrict__ Wt, int K, int N) {
    __shared__ float t[32][33];
    int n0 = blockIdx.x * 32, k0 = blockIdx.y * 32;
    int c = threadIdx.x & 31, r = threadIdx.x >> 5;   // r: 0..7
    for (int i = 0; i < 4; i++)
        t[r + i * 8][c] = W[(size_t)(k0 + r + i * 8) * N + n0 + c];
    __syncthreads();
    for (int i = 0; i < 4; i++)
        Wt[(size_t)(n0 + r + i * 8) * K + k0 + c] = f2bf(t[c][r + i * 8]);
}

// ---- transpose 512x512 W -> STACKED hi/lo bf16: q/k interleaved per 256-chunk ----
__global__ __launch_bounds__(256) void transpose_split_stk_kernel(
    const float* __restrict__ W, unsigned short* __restrict__ WtH,
    unsigned short* __restrict__ WtL, int which) {
    __shared__ float t[32][33];
    int n0 = blockIdx.x * 32, k0 = blockIdx.y * 32;
    int c = threadIdx.x & 31, r = threadIdx.x >> 5;
    for (int i = 0; i < 4; i++)
        t[r + i * 8][c] = W[(size_t)(k0 + r + i * 8) * DMODEL + n0 + c];
    __syncthreads();
    for (int i = 0; i < 4; i++) {
        int n = n0 + r + i * 8;
        int row = (n & 255) + ((n >> 8) * 512) + which * 256;
        float v = t[c][r + i * 8];
        unsigned short h = f2bf(v);
        size_t o = (size_t)row * DMODEL + k0 + c;
        WtH[o] = h;
        WtL[o] = f2bf(v - bf2f(h));
    }
}

// ---------------- stacked bias ----------------
__global__ void stack_bias_kernel(const float* __restrict__ bq,
                                  const float* __restrict__ bk, float* __restrict__ bstk) {
    int i = blockIdx.x * 256 + threadIdx.x;     // 0..1023
    if (i >= 1024) return;
    int c = i >> 9, j = i & 511;
    bstk[i] = (j < 256) ? bq[c * 256 + j] : bk[c * 256 + (j - 256)];
}

// ---------------- Wvo = Wv @ Wo (fp32, per layer; 512 blocks) ----------------
__global__ __launch_bounds__(256) void wvo_kernel(
    const float* __restrict__ Wv, const float* __restrict__ Wo,
    float* __restrict__ Wvo) {
    __shared__ float row[DMODEL];
    int k = blockIdx.x;
    int tid = threadIdx.x;
    for (int j = tid; j < DMODEL; j += 256) row[j] = Wv[(size_t)k * DMODEL + j];
    __syncthreads();
    float a0 = 0.f, a1 = 0.f;
    for (int j = 0; j < DMODEL; j++) {
        float wv = row[j];
        a0 += wv * Wo[(size_t)j * DMODEL + tid];
        a1 += wv * Wo[(size_t)j * DMODEL + tid + 256];
    }
    Wvo[(size_t)k * DMODEL + tid] = a0;
    Wvo[(size_t)k * DMODEL + tid + 256] = a1;
}

// ---------------- cb = bv @ Wo + bo ----------------
__global__ void cbias_kernel(const float* __restrict__ bv, const float* __restrict__ Wo,
                             const float* __restrict__ bo, float* __restrict__ cb) {
    int n = blockIdx.x * 256 + threadIdx.x;
    if (n >= DMODEL) return;
    float acc = bo[n];
    for (int j = 0; j < DMODEL; j++) acc += bv[j] * Wo[(size_t)j * DMODEL + n];
    cb[n] = acc;
}

// ---------------- bf16 MFMA GEMM (register staging, round-7 proven) ----------
// res/Cout may alias at identical indices (in-place z): read-before-write per thread.
#define BK 32
__global__ __launch_bounds__(256) void gemm_mfma_kernel(
    const unsigned short* __restrict__ A, const unsigned short* __restrict__ Wt,
    const float* __restrict__ bias, const float* res,
    void* Cout, int M, int N, int K, int act, int outMode)
{
    __shared__ unsigned short As[128 * 40];
    __shared__ unsigned short Bs[128 * 40];
    int tid = threadIdx.x;
    int wave = tid >> 6, lane = tid & 63;
    int wm = wave & 1, wn = wave >> 1;
    int bm = blockIdx.y * 128, bn = blockIdx.x * 128;

    int r0 = tid >> 2;              // 0..63
    int koff = (tid & 3) * 8;       // 0,8,16,24
    const unsigned short* Ag = A  + (size_t)(bm + r0) * K + koff;
    const unsigned short* Bg = Wt + (size_t)(bn + r0) * K + koff;

    f32x4 acc[4][4] = {};
    int frow = lane & 15, fk = (lane >> 4) * 8;

    for (int k0 = 0; k0 < K; k0 += BK) {
        bf16x8 a0 = *(const bf16x8*)(Ag + k0);
        bf16x8 a1 = *(const bf16x8*)(Ag + (size_t)64 * K + k0);
        bf16x8 b0 = *(const bf16x8*)(Bg + k0);
        bf16x8 b1 = *(const bf16x8*)(Bg + (size_t)64 * K + k0);
        __syncthreads();
        *(bf16x8*)&As[r0 * 40 + koff]        = a0;
        *(bf16x8*)&As[(r0 + 64) * 40 + koff] = a1;
        *(bf16x8*)&Bs[r0 * 40 + koff]        = b0;
        *(bf16x8*)&Bs[(r0 + 64) * 40 + koff] = b1;
        __syncthreads();
        bf16x8 af[4], bfv[4];
#pragma unroll
        for (int mi = 0; mi < 4; mi++)
            af[mi] = *(const bf16x8*)&As[(wm * 64 + mi * 16 + frow) * 40 + fk];
#pragma unroll
        for (int nj = 0; nj < 4; nj++)
            bfv[nj] = *(const bf16x8*)&Bs[(wn * 64 + nj * 16 + frow) * 40 + fk];
#pragma unroll
        for (int mi = 0; mi < 4; mi++)
#pragma unroll
            for (int nj = 0; nj < 4; nj++)
                acc[mi][nj] = __builtin_amdgcn_mfma_f32_16x16x32_bf16(
                    af[mi], bfv[nj], acc[mi][nj], 0, 0, 0);
    }

    int lrow = (lane >> 4) * 4, lcol = lane & 15;
#pragma unroll
    for (int mi = 0; mi < 4; mi++) {
        int row0 = bm + wm * 64 + mi * 16 + lrow;
#pragma unroll
        for (int nj = 0; nj < 4; nj++) {
            int col = bn + wn * 64 + nj * 16 + lcol;
            float bv = bias ? bias[col] : 0.f;
            f32x4 v = acc[mi][nj];
#pragma unroll
            for (int r = 0; r < 4; r++) {
                int row = row0 + r;
                float x = v[r] + bv;
                if (res) x += res[(size_t)row * N + col];
                if (act == 1) x = gelu_f(x);
                if (outMode == 0) ((float*)Cout)[(size_t)row * N + col] = x;
                else              ((unsigned short*)Cout)[(size_t)row * N + col] = f2bf(x);
            }
        }
    }
}

// ---------------- split-precision MFMA GEMM for q/k (fp32-accurate) ----------
// Output fp32 TRANSPOSED: Ct[col*M + row]. With stacked weights N=512 covers q&k.
__global__ __launch_bounds__(256) void gemm_qk_split_kernel(
    const unsigned short* __restrict__ Ahi, const unsigned short* __restrict__ Alo,
    const unsigned short* __restrict__ Whi, const unsigned short* __restrict__ Wlo,
    const float* __restrict__ bias, float* __restrict__ Ct, int M, int K)
{
    __shared__ unsigned short AsH[128 * 40];
    __shared__ unsigned short AsL[128 * 40];
    __shared__ unsigned short BsH[128 * 40];
    __shared__ unsigned short BsL[128 * 40];
    int tid = threadIdx.x;
    int wave = tid >> 6, lane = tid & 63;
    int wm = wave & 1, wn = wave >> 1;
    int bm = blockIdx.y * 128, bn = blockIdx.x * 128;

    int r0 = tid >> 2;
    int koff = (tid & 3) * 8;
    const unsigned short* AgH = Ahi + (size_t)(bm + r0) * K + koff;
    const unsigned short* AgL = Alo + (size_t)(bm + r0) * K + koff;
    const unsigned short* BgH = Whi + (size_t)(bn + r0) * K + koff;
    const unsigned short* BgL = Wlo + (size_t)(bn + r0) * K + koff;

    f32x4 acc[4][4] = {};
    int frow = lane & 15, fk = (lane >> 4) * 8;

    for (int k0 = 0; k0 < K; k0 += BK) {
        bf16x8 ah0 = *(const bf16x8*)(AgH + k0);
        bf16x8 ah1 = *(const bf16x8*)(AgH + (size_t)64 * K + k0);
        bf16x8 al0 = *(const bf16x8*)(AgL + k0);
        bf16x8 al1 = *(const bf16x8*)(AgL + (size_t)64 * K + k0);
        bf16x8 bh0 = *(const bf16x8*)(BgH + k0);
        bf16x8 bh1 = *(const bf16x8*)(BgH + (size_t)64 * K + k0);
        bf16x8 bl0 = *(const bf16x8*)(BgL + k0);
        bf16x8 bl1 = *(const bf16x8*)(BgL + (size_t)64 * K + k0);
        __syncthreads();
        *(bf16x8*)&AsH[r0 * 40 + koff]        = ah0;
        *(bf16x8*)&AsH[(r0 + 64) * 40 + koff] = ah1;
        *(bf16x8*)&AsL[r0 * 40 + koff]        = al0;
        *(bf16x8*)&AsL[(r0 + 64) * 40 + koff] = al1;
        *(bf16x8*)&BsH[r0 * 40 + koff]        = bh0;
        *(bf16x8*)&BsH[(r0 + 64) * 40 + koff] = bh1;
        *(bf16x8*)&BsL[r0 * 40 + koff]        = bl0;
        *(bf16x8*)&BsL[(r0 + 64) * 40 + koff] = bl1;
        __syncthreads();
        bf16x8 afh[4], afl[4], bfh[4], bfl[4];
#pragma unroll
        for (int mi = 0; mi < 4; mi++) {
            int o = (wm * 64 + mi * 16 + frow) * 40 + fk;
            afh[mi] = *(const bf16x8*)&AsH[o];
            afl[mi] = *(const bf16x8*)&AsL[o];
        }
#pragma unroll
        for (int nj = 0; nj < 4; nj++) {
            int o = (wn * 64 + nj * 16 + frow) * 40 + fk;
            bfh[nj] = *(const bf16x8*)&BsH[o];
            bfl[nj] = *(const bf16x8*)&BsL[o];
        }
#pragma unroll
        for (int mi = 0; mi < 4; mi++)
#pragma unroll
            for (int nj = 0; nj < 4; nj++) {
                acc[mi][nj] = __builtin_amdgcn_mfma_f32_16x16x32_bf16(
                    afh[mi], bfh[nj], acc[mi][nj], 0, 0, 0);
                acc[mi][nj] = __builtin_amdgcn_mfma_f32_16x16x32_bf16(
                    afh[mi], bfl[nj], acc[mi][nj], 0, 0, 0);
                acc[mi][nj] = __builtin_amdgcn_mfma_f32_16x16x32_bf16(
                    afl[mi], bfh[nj], acc[mi][nj], 0, 0, 0);
            }
    }

    int lrow = (lane >> 4) * 4, lcol = lane & 15;
#pragma unroll
    for (int mi = 0; mi < 4; mi++) {
        int row0 = bm + wm * 64 + mi * 16 + lrow;
#pragma unroll
        for (int nj = 0; nj < 4; nj++) {
            int col = bn + wn * 64 + nj * 16 + lcol;
            float bv = bias ? bias[col] : 0.f;
            f32x4 v = acc[mi][nj];
#pragma unroll
            for (int r = 0; r < 4; r++)
                Ct[(size_t)col * M + row0 + r] = v[r] + bv;
        }
    }
}

// ---------------- 2560-pt FFT (radix-5 + sincos twiddle + 9x radix-2 Stockham) --
// NT = threads cooperating; round-10 proven math, twice the lanes this round.
template<int NT>
__device__ void fft2560(float2* bufA, float2* bufB, const float2* w512, int tid) {
    const float w5r[5] = { 1.f,  0.30901699437494742f, -0.80901699437494742f,
                          -0.80901699437494742f,  0.30901699437494742f };
    const float w5i[5] = { 0.f, -0.95105651629515357f, -0.58778525229247312f,
                           0.58778525229247312f,  0.95105651629515357f };
    __syncthreads();
    const float TWO_PI = 6.283185307179586f;
    for (int j = tid; j < SEQ; j += NT) {
        int k1 = j >> 9, n2 = j & 511;
        float ar = 0.f, ai = 0.f;
        for (int n1 = 0; n1 < 5; n1++) {
            int m = (n1 * k1) % 5;
            float2 x = bufA[n1 * 512 + n2];
            ar += x.x * w5r[m] - x.y * w5i[m];
            ai += x.x * w5i[m] + x.y * w5r[m];
        }
        float ang = -TWO_PI * (float)(n2 * k1) / 2560.0f;
        float sn, cs;
        sincosf(ang, &sn, &cs);
        bufB[j] = make_float2(ar * cs - ai * sn, ar * sn + ai * cs);
    }
    __syncthreads();
    float2* X = bufB;
    float2* Y = bufA;
    int n = 512, logs = 0;
    for (int st = 0; st < 9; st++) {
        int m = n >> 1;
        int s = 1 << logs;
        for (int t = tid; t < 1280; t += NT) {
            int sub = t >> 8;
            int r = t & 255;
            int p = r >> logs;
            int q = r & (s - 1);
            int base = sub << 9;
            float2 a = X[base + q + s * p];
            float2 b = X[base + q + s * (p + m)];
            float2 sum = make_float2(a.x + b.x, a.y + b.y);
            float2 dif = make_float2(a.x - b.x, a.y - b.y);
            float2 w = w512[p << logs];
            Y[base + q + s * (2 * p)]     = sum;
            Y[base + q + s * (2 * p + 1)] = make_float2(dif.x * w.x - dif.y * w.y,
                                                        dif.x * w.y + dif.y * w.x);
        }
        __syncthreads();
        float2* tmp = X; X = Y; Y = tmp;
        n >>= 1; logs++;
    }
    // result in bufA: bufA[k1*512 + k2] = DFT[k1 + 5*k2]
}

// one workgroup (512 threads) per (DGRP-channel group, b): packed z = q + i*k,
// register-accumulated P[f], one atomicAdd pair per freq at the end.
__global__ __launch_bounds__(FFT_NT) void fft_fwd_kernel(
    const float* __restrict__ qt, const float* __restrict__ kt, float* __restrict__ Z)
{
    __shared__ float2 bufA[SEQ];
    __shared__ float2 bufB[SEQ];
    __shared__ float2 w512[256];
    int d0 = blockIdx.x * DGRP;
    int b = blockIdx.y;
    int tid = threadIdx.x;
    if (tid < 256) {
        float sn, cs;
        sincosf(-6.283185307179586f * (float)tid / 512.0f, &sn, &cs);
        w512[tid] = make_float2(cs, sn);
    }
    float accR[5], accI[5];
#pragma unroll
    for (int j = 0; j < 5; j++) { accR[j] = 0.f; accI[j] = 0.f; }

    for (int col = 0; col < DGRP; col++) {
        const float* qcol = qt + (size_t)(d0 + col) * MROWS + (size_t)b * SEQ;
        const float* kcol = kt + (size_t)(d0 + col) * MROWS + (size_t)b * SEQ;
        __syncthreads();    // previous epilogue finished reading bufA
        for (int i = tid; i < SEQ; i += FFT_NT)
            bufA[i] = make_float2(qcol[i], kcol[i]);
        fft2560<FFT_NT>(bufA, bufB, w512, tid);   // entry barrier publishes writes
#pragma unroll
        for (int j = 0; j < 5; j++) {
            int f = tid + FFT_NT * j;
            int fpos = (f % 5) * 512 + (f / 5);
            int g = f ? (SEQ - f) : 0;
            int gpos = (g % 5) * 512 + (g / 5);
            float2 Z1 = bufA[fpos], Z2 = bufA[gpos];
            accR[j] += 0.5f * (Z1.x * Z2.y + Z1.y * Z2.x);            // Im(Z1*Z2)/2
            accI[j] += 0.25f * ((Z1.x * Z1.x + Z1.y * Z1.y)
                              - (Z2.x * Z2.x + Z2.y * Z2.y));         // (|Z1|^2-|Z2|^2)/4
        }
    }
#pragma unroll
    for (int j = 0; j < 5; j++) {
        int f = tid + FFT_NT * j;
        int fpos = (f % 5) * 512 + (f / 5);
        atomicAdd(&Z[((size_t)b * SEQ + fpos) * 2 + 0], accR[j]);
        atomicAdd(&Z[((size_t)b * SEQ + fpos) * 2 + 1], accI[j]);
    }
}

__global__ __launch_bounds__(FFT_NT) void fft_inv_kernel(
    const float* __restrict__ Z, float* __restrict__ mc)
{
    __shared__ float2 bufA[SEQ];
    __shared__ float2 bufB[SEQ];
    __shared__ float2 w512[256];
    int b = blockIdx.x;
    int tid = threadIdx.x;
    if (tid < 256) {
        float sn, cs;
        sincosf(-6.283185307179586f * (float)tid / 512.0f, &sn, &cs);
        w512[tid] = make_float2(cs, sn);
    }
    for (int i = tid; i < SEQ; i += FFT_NT) {
        int k1 = i % 5, k2 = i / 5;
        float zr = Z[((size_t)b * SEQ + k1 * 512 + k2) * 2 + 0];
        float zi = Z[((size_t)b * SEQ + k1 * 512 + k2) * 2 + 1];
        bufA[i] = make_float2(zr, -zi);
    }
    fft2560<FFT_NT>(bufA, bufB, w512, tid);
    const float scale = 1.0f / (2560.0f * 512.0f);
    for (int j = tid; j < SEQ; j += FFT_NT) {
        int k1 = j >> 9, k2 = j & 511;
        mc[(size_t)b * SEQ + k1 + 5 * k2] = bufA[j].x * scale;
    }
}

// ---------------- top-7 + softmax per batch ----------------
__global__ __launch_bounds__(256) void topk_kernel(
    const float* __restrict__ mc, float* __restrict__ wts, int* __restrict__ dels)
{
    __shared__ float cv[SEQ];
    __shared__ float rv[256];
    __shared__ int   ri[256];
    __shared__ float topv[TOPK];
    __shared__ int   topi[TOPK];
    int b = blockIdx.x, tid = threadIdx.x;
    for (int i = tid; i < SEQ; i += 256) cv[i] = mc[(size_t)b * SEQ + i];
    __syncthreads();
    for (int it = 0; it < TOPK; it++) {
        float bv = -2e30f; int bi = 1 << 30;
        for (int i = tid; i < SEQ; i += 256) {
            float v = cv[i];
            if (v > bv || (v == bv && i < bi)) { bv = v; bi = i; }
        }
        rv[tid] = bv; ri[tid] = bi;
        __syncthreads();
        for (int off = 128; off > 0; off >>= 1) {
            if (tid < off) {
                float v2 = rv[tid + off]; int i2 = ri[tid + off];
                if (v2 > rv[tid] || (v2 == rv[tid] && i2 < ri[tid])) {
                    rv[tid] = v2; ri[tid] = i2;
                }
            }
            __syncthreads();
        }
        if (tid == 0) { topv[it] = rv[0]; topi[it] = ri[0]; cv[ri[0]] = -1e30f; }
        __syncthreads();
    }
    if (tid == 0) {
        float mx = topv[0];
        float e[TOPK], ssum = 0.f;
        for (int i = 0; i < TOPK; i++) { e[i] = expf(topv[i] - mx); ssum += e[i]; }
        for (int i = 0; i < TOPK; i++) {
            wts[b * TOPK + i] = e[i] / ssum;
            dels[b * TOPK + i] = topi[i];
        }
    }
}

// ---------------- fused delay aggregation + bias + residual ------------------
__global__ void agg_res_kernel(const float* __restrict__ u, const float* __restrict__ x,
                               const float* __restrict__ cb,
                               const float* __restrict__ wts, const int* __restrict__ dels,
                               float* __restrict__ x1) {
    size_t idx = (size_t)blockIdx.x * 256 + threadIdx.x;
    if (idx >= SD) return;
    int d = idx & (DMODEL - 1);
    size_t r = idx >> 9;
    int s = (int)(r % SEQ);
    int b = (int)(r / SEQ);
    float acc = cb[d] + x[idx];
    for (int i = 0; i < TOPK; i++) {
        int del = dels[b * TOPK + i];
        float w = wts[b * TOPK + i];
        int ss = s + del; if (ss >= SEQ) ss -= SEQ;
        acc += w * u[((size_t)b * SEQ + ss) * DMODEL + d];
    }
    x1[idx] = acc;
}

// ---------------- x - moving_avg(x): running-window (3 reads/elem vs 25) -----
// grid (20, 2, 16). NOTE: out/o1/o2 must NOT alias x.
#define MA_MODE_PLAIN 0
#define MA_MODE_BF    1
#define MA_MODE_SPLIT 2
template<int MODE>
__device__ __forceinline__ void ma_run_body(
    const float* __restrict__ x, float* __restrict__ out,
    unsigned short* __restrict__ o1, unsigned short* __restrict__ o2)
{
    int tid = threadIdx.x;
    int s0 = blockIdx.x * 128;
    int d  = blockIdx.y * 256 + tid;
    int b  = blockIdx.z;
    const float* xb = x + (size_t)b * SEQ * DMODEL + d;
    float sum = 0.f;
#pragma unroll
    for (int j = -12; j <= 12; j++) {
        int ss = s0 + j;
        ss = ss < 0 ? 0 : (ss > SEQ - 1 ? SEQ - 1 : ss);
        sum += xb[(size_t)ss * DMODEL];
    }
    for (int s = s0; s < s0 + 128; s++) {
        float v = xb[(size_t)s * DMODEL] - sum * (1.0f / 25.0f);
        size_t o = ((size_t)b * SEQ + s) * DMODEL + d;
        out[o] = v;
        if (MODE == MA_MODE_BF) {
            o1[o] = f2bf(v);
        } else if (MODE == MA_MODE_SPLIT) {
            unsigned short h = f2bf(v);
            o1[o] = h;
            o2[o] = f2bf(v - bf2f(h));
        }
        int add = s + 13; if (add > SEQ - 1) add = SEQ - 1;
        int sub = s - 12; if (sub < 0) sub = 0;
        sum += xb[(size_t)add * DMODEL] - xb[(size_t)sub * DMODEL];
    }
}
__global__ __launch_bounds__(256) void ma_sub_kernel(
    const float* __restrict__ x, float* __restrict__ out) {
    ma_run_body<MA_MODE_PLAIN>(x, out, nullptr, nullptr);
}
__global__ __launch_bounds__(256) void ma_sub_bf_kernel(
    const float* __restrict__ x, float* __restrict__ out,
    unsigned short* __restrict__ obf) {
    ma_run_body<MA_MODE_BF>(x, out, obf, nullptr);
}
__global__ __launch_bounds__(256) void ma_sub_split_kernel(
    const float* __restrict__ x, float* __restrict__ out,
    unsigned short* __restrict__ hi, unsigned short* __restrict__ lo) {
    ma_run_body<MA_MODE_SPLIT>(x, out, hi, lo);
}

// ---------------- layernorm over last dim ----------------
__global__ __launch_bounds__(256) void ln_kernel(
    const float* __restrict__ x, const float* __restrict__ g,
    const float* __restrict__ be, float* __restrict__ xh)
{
    int row = blockIdx.x;
    int tid = threadIdx.x;
    __shared__ float red[256];
    const float* xr = x + (size_t)row * DMODEL;
    float v0 = xr[tid], v1 = xr[tid + 256];
    red[tid] = v0 + v1;
    __syncthreads();
    for (int off = 128; off > 0; off >>= 1) {
        if (tid < off) red[tid] += red[tid + off];
        __syncthreads();
    }
    float mu = red[0] / (float)DMODEL;
    __syncthreads();
    float d0 = v0 - mu, d1 = v1 - mu;
    red[tid] = d0 * d0 + d1 * d1;
    __syncthreads();
    for (int off = 128; off > 0; off >>= 1) {
        if (tid < off) red[tid] += red[tid + off];
        __syncthreads();
    }
    float inv = rsqrtf(red[0] / (float)DMODEL + 1e-5f);
    xh[(size_t)row * DMODEL + tid]       = d0 * inv * g[tid] + be[tid];
    xh[(size_t)row * DMODEL + tid + 256] = d1 * inv * g[tid + 256] + be[tid + 256];
}

// ---------------- per-(b,d) mean over sequence (parallel, atomic partials) ----
__global__ __launch_bounds__(256) void colmean_kernel(
    const float* __restrict__ xh, float* __restrict__ cm) {
    int idx = blockIdx.x * 256 + threadIdx.x;   // (b,d) 0..8191
    int d = idx & (DMODEL - 1), b = idx >> 9;
    int s0 = blockIdx.y * 128;
    float acc = 0.f;
    for (int s = s0; s < s0 + 128; s++)
        acc += xh[((size_t)b * SEQ + s) * DMODEL + d];
    atomicAdd(&cm[idx], acc * (1.0f / (float)SEQ));
}

__global__ __launch_bounds__(256) void final_kernel(
    const float* __restrict__ xh, const float* __restrict__ cm,
    const float* __restrict__ Wp, const float* __restrict__ bp,
    float* __restrict__ out)
{
    int b = blockIdx.y, chunk = blockIdx.x;
    int tid = threadIdx.x;
    const size_t per = (size_t)SEQ * DMODEL / 64;
    size_t start = (size_t)chunk * per;
    float acc = 0.f;
    for (size_t i = start + tid; i < start + per; i += 256) {
        int d = (int)(i & (DMODEL - 1));
        float v = xh[(size_t)b * SEQ * DMODEL + i] - cm[b * DMODEL + d];
        acc += gelu_f(v) * Wp[i];
    }
    __shared__ float red[256];
    red[tid] = acc;
    __syncthreads();
    for (int off = 128; off > 0; off >>= 1) {
        if (tid < off) red[tid] += red[tid + off];
        __syncthreads();
    }
    if (tid == 0) {
        atomicAdd(&out[b], red[0]);
        if (chunk == 0) atomicAdd(&out[b], bp[0]);
    }
}

// ---------------- orchestration: 3-buffer rotation, NO input/output aliasing ----
// Per layer: X = x fp32 | HL = x hi/lo (-> x1 fp32 -> gelu bf16) | S = qtf/ktf
// -> u -> x2 bf16 -> h out. X and S swap each layer.
extern "C" void kernel_launch(void* const* d_in, const int* in_sizes, int n_in,
                              void* d_out, int out_size, void* d_ws, size_t ws_size,
                              hipStream_t stream) {
    const float* data  = (const float*)d_in[0];
    const float* mask  = (const float*)d_in[1];
    const float* Wemb  = (const float*)d_in[2];
    const float* Wq    = (const float*)d_in[3];
    const float* bq    = (const float*)d_in[4];
    const float* Wk    = (const float*)d_in[5];
    const float* bk    = (const float*)d_in[6];
    const float* Wv    = (const float*)d_in[7];
    const float* bv    = (const float*)d_in[8];
    const float* Wo    = (const float*)d_in[9];
    const float* bo    = (const float*)d_in[10];
    const float* Wc1   = (const float*)d_in[11];
    const float* Wc2   = (const float*)d_in[12];
    const float* gamma = (const float*)d_in[13];
    const float* beta  = (const float*)d_in[14];
    const float* Wp    = (const float*)d_in[15];
    const float* bp    = (const float*)d_in[16];
    float* out = (float*)d_out;

    float* buf0 = (float*)d_ws;
    float* buf1 = buf0 + SD;
    float* buf2 = buf1 + SD;

    unsigned short* WstkH = (unsigned short*)(buf2 + SD);   // 2*512*512 stacked q/k hi
    unsigned short* WstkL = WstkH + 2 * DMODEL * DMODEL;    // stacked q/k lo
    unsigned short* Wvot  = WstkL + 2 * DMODEL * DMODEL;    // bf16 [N][K] of Wv@Wo
    unsigned short* Wc1t  = Wvot + DMODEL * DMODEL;         // [2048][512]
    unsigned short* Wc2t  = Wc1t + (size_t)DMODEL * DFF;    // [512][2048]
    float* WvoF = (float*)(Wc2t + (size_t)DMODEL * DFF);    // fp32 Wv@Wo (512x512)
    float* CB   = WvoF + (size_t)DMODEL * DMODEL;           // cb = bv@Wo + bo
    float* Bstk = CB + DMODEL;                              // stacked q/k bias (1024)
    float* Zb = Bstk + 1024;
    float* MC = Zb + (size_t)BATCH * SEQ * 2;
    float* WT = MC + (size_t)BATCH * SEQ;
    int*   DL = (int*)(WT + BATCH * TOPK);
    float* CM = (float*)(DL + BATCH * TOPK);

    const int NB  = (int)((SD + 255) / 256);
    const int NB4 = (int)((SD / 4 + 255) / 256);
    dim3 gMA(SEQ / 128, 2, BATCH);              // (20, 2, 16) running-window MA

    float* X  = buf0;   // x fp32
    float* HL = buf1;   // hi/lo pool
    float* S  = buf2;   // scratch

    embed_kernel<<<NB, 256, 0, stream>>>(data, mask, Wemb, X);
    conv_split_kernel<<<NB4, 256, 0, stream>>>(
        X, (unsigned short*)HL + SD, (unsigned short*)HL, SD);  // hi -> upper, lo -> lower

    dim3 gSq(DMODEL / 128, MROWS / 128);        // (4, 320)
    dim3 gF1(DFF / 128, FFN_CHUNK / 128);       // (16, 160)
    dim3 gF2(DMODEL / 128, FFN_CHUNK / 128);    // (4, 160)

    for (int l = 0; l < NLAYERS; l++) {
        const float* wq = Wq + (size_t)l * DMODEL * DMODEL;
        const float* wk = Wk + (size_t)l * DMODEL * DMODEL;
        const float* wv = Wv + (size_t)l * DMODEL * DMODEL;
        const float* wo = Wo + (size_t)l * DMODEL * DMODEL;
        const float* bqL = bq + (size_t)l * DMODEL;
        const float* bkL = bk + (size_t)l * DMODEL;
        const float* bvL = bv + (size_t)l * DMODEL;
        const float* boL = bo + (size_t)l * DMODEL;
        const float* wc1 = Wc1 + (size_t)l * DMODEL * DFF;
        const float* wc2 = Wc2 + (size_t)l * DFF * DMODEL;

        unsigned short* Lbf = (unsigned short*)HL;      // x_lo (lower half)
        unsigned short* Hbf = Lbf + SD;                 // x_hi (upper half)
        float* qtf = S;                                 // q cols (MROWS*256)
        float* ktf = S + (size_t)MROWS * CHUNK_D;       // k cols

        dim3 gT(DMODEL / 32, DMODEL / 32);
        transpose_split_stk_kernel<<<gT, 256, 0, stream>>>(wq, WstkH, WstkL, 0);
        transpose_split_stk_kernel<<<gT, 256, 0, stream>>>(wk, WstkH, WstkL, 1);
        stack_bias_kernel<<<4, 256, 0, stream>>>(bqL, bkL, Bstk);
        wvo_kernel<<<DMODEL, 256, 0, stream>>>(wv, wo, WvoF);
        transpose_bf16_kernel<<<gT, 256, 0, stream>>>(WvoF, Wvot, DMODEL, DMODEL);
        cbias_kernel<<<2, 256, 0, stream>>>(bvL, wo, boL, CB);
        transpose_bf16_kernel<<<dim3(DFF / 32, DMODEL / 32), 256, 0, stream>>>(wc1, Wc1t, DMODEL, DFF);
        transpose_bf16_kernel<<<dim3(DMODEL / 32, DFF / 32), 256, 0, stream>>>(wc2, Wc2t, DFF, DMODEL);

        // q&k stacked: one split GEMM per 256-col chunk into S (N=512 covers both)
        hipMemsetAsync(Zb, 0, (size_t)BATCH * SEQ * 2 * sizeof(float), stream);
        for (int c = 0; c < DMODEL / CHUNK_D; c++) {
            gemm_qk_split_kernel<<<gSq, 256, 0, stream>>>(
                Hbf, Lbf, WstkH + (size_t)c * 512 * DMODEL,
                WstkL + (size_t)c * 512 * DMODEL, Bstk + c * 512,
                S, MROWS, DMODEL);
            fft_fwd_kernel<<<dim3(CHUNK_D / DGRP, BATCH), FFT_NT, 0, stream>>>(qtf, ktf, Zb);
        }
        fft_inv_kernel<<<BATCH, FFT_NT, 0, stream>>>(Zb, MC);
        topk_kernel<<<BATCH, 256, 0, stream>>>(MC, WT, DL);

        // u = x@(Wv@Wo) -> S fp32 (qtf/ktf dead)
        gemm_mfma_kernel<<<gSq, 256, 0, stream>>>(Hbf, Wvot, nullptr, nullptr, S,
                                                  MROWS, DMODEL, DMODEL, 0, 0);
        // x1 = sum w_i roll(u) + cb + x -> HL as fp32 (x hi/lo dead)
        agg_res_kernel<<<NB, 256, 0, stream>>>(S, X, CB, WT, DL, HL);
        // x2 = x1 - MA(x1): fp32 -> X (x dead), bf16 -> S (u dead). No aliasing.
        ma_sub_bf_kernel<<<gMA, 256, 0, stream>>>(HL, X, (unsigned short*)S);
        // FFN in 2 row-chunks: gelu bf16 fills HL exactly (x1 dead);
        // z in-place over X (res==out, same-index).
        for (int c = 0; c < MROWS / FFN_CHUNK; c++) {
            const unsigned short* x2c = (unsigned short*)S + (size_t)c * FFN_CHUNK * DMODEL;
            float* xz = X + (size_t)c * FFN_CHUNK * DMODEL;
            gemm_mfma_kernel<<<gF1, 256, 0, stream>>>(x2c, Wc1t, nullptr, nullptr,
                                                      (unsigned short*)HL,
                                                      FFN_CHUNK, DFF, DMODEL, 1, 1);
            gemm_mfma_kernel<<<gF2, 256, 0, stream>>>((unsigned short*)HL, Wc2t,
                                                      nullptr, xz, xz,
                                                      FFN_CHUNK, DMODEL, DFF, 0, 0);
        }
        // h = z - MA(z): z in X -> h fp32 -> S (+ hi/lo -> HL if another layer)
        if (l + 1 < NLAYERS)
            ma_sub_split_kernel<<<gMA, 256, 0, stream>>>(
                X, S, (unsigned short*)HL + SD, (unsigned short*)HL);
        else
            ma_sub_kernel<<<gMA, 256, 0, stream>>>(X, S);
        // rotate: next layer's x is in S
        float* tmp = X; X = S; S = tmp;
    }

    // final h is in X; use HL for xh
    ln_kernel<<<MROWS, 256, 0, stream>>>(X, gamma, beta, HL);
    hipMemsetAsync(CM, 0, (size_t)BATCH * DMODEL * sizeof(float), stream);
    colmean_kernel<<<dim3(32, 20), 256, 0, stream>>>(HL, CM);
    hipMemsetAsync(out, 0, (size_t)out_size * sizeof(float), stream);
    final_kernel<<<dim3(64, BATCH), 256, 0, stream>>>(HL, CM, Wp, bp, out);
}

// Round 16
// 2295.139 us; speedup vs baseline: 1.3198x; 1.0459x over previous
//
#include <hip/hip_runtime.h>
#include <math.h>

// ---------------- problem constants ----------------
#define BATCH 16
#define L_CYC 20
#define CDL 128
#define SEQ 2560            // L_CYC * CDL
#define ENC_IN 3
#define DMODEL 512
#define DFF 2048
#define NLAYERS 2
#define TOPK 7
#define MROWS (BATCH*SEQ)   // 40960
#define SD ((size_t)BATCH * SEQ * DMODEL)   // 20,971,520
#define FFN_CHUNK 20480     // 2 chunks; 20480*2048 ushorts == SD*4 bytes exactly
#define CHUNK_D 256         // q/k column-chunk width
#define DGRP 8              // FFT channels per workgroup (proven)
#define FFT_NT 512          // threads per FFT block (round-15 proven)

typedef short bf16x8 __attribute__((ext_vector_type(8)));
typedef float f32x4 __attribute__((ext_vector_type(4)));

__device__ __forceinline__ float gelu_f(float x) {
    return 0.5f * x * (1.0f + erff(x * 0.70710678118654752f));
}
__device__ __forceinline__ unsigned short f2bf(float f) {
    unsigned int u = __float_as_uint(f);
    u += 0x7fff + ((u >> 16) & 1);          // RNE
    return (unsigned short)(u >> 16);
}
__device__ __forceinline__ float bf2f(unsigned short h) {
    return __uint_as_float(((unsigned int)h) << 16);
}
// XCD-aware swizzle: 1-D block id p -> (row-group g, n-tile n) with all G
// n-tiles of g on the same XCD (round-robin p%8). Requires gridM % 8 == 0.
__device__ __forceinline__ void xcd_map(int p, int G, int& g, int& n) {
    int a = p >> 3;
    n = a % G;
    g = (a / G) * 8 + (p & 7);
}

// ---------------- embed: mask + reshape + circular conv1d(k=3) ----------------
__global__ __launch_bounds__(256) void embed_kernel(
    const float* __restrict__ data, const float* __restrict__ mask,
    const float* __restrict__ Wemb, float* __restrict__ h) {
    __shared__ float xv[9];     // [c*3 + t]
    size_t idx = (size_t)blockIdx.x * 256 + threadIdx.x;
    size_t r = idx >> 9;
    int s = (int)(r % SEQ);
    int b = (int)(r / SEQ);
    int tid = threadIdx.x;
    if (tid < 9) {
        int t = tid / 3, c = tid % 3;
        int u = s - 1 + t;
        if (u < 0) u += SEQ;
        if (u >= SEQ) u -= SEQ;
        int cyc = u >> 7, pos = u & 127;
        float mk = mask[b * L_CYC + cyc];
        xv[c * 3 + t] = (mk == 0.f) ? 0.f
            : data[(((size_t)b * L_CYC + cyc) * ENC_IN + c) * CDL + pos];
    }
    __syncthreads();
    int dm = idx & (DMODEL - 1);
    float acc = 0.f;
#pragma unroll
    for (int j = 0; j < 9; j++) acc += xv[j] * Wemb[dm * 9 + j];
    h[idx] = acc;
}

// ---------------- fp32 -> bf16 hi + lo (split precision) ----------------
__global__ void conv_split_kernel(const float* __restrict__ in,
                                  unsigned short* __restrict__ hi,
                                  unsigned short* __restrict__ lo, size_t n) {
    size_t i = ((size_t)blockIdx.x * 256 + threadIdx.x) * 4;
    if (i >= n) return;
    float4 v = *(const float4*)(in + i);
    float vv[4] = { v.x, v.y, v.z, v.w };
#pragma unroll
    for (int j = 0; j < 4; j++) {
        unsigned short h = f2bf(vv[j]);
        hi[i + j] = h;
        lo[i + j] = f2bf(vv[j] - bf2f(h));
    }
}

// ---------------- transpose W[K][N] fp32 -> Wt[N][K] bf16 ----------------
__global__ __launch_bounds__(256) void transpose_bf16_kernel(
    const float* __restrict__ W, unsigned short* __restrict__ Wt, int K, int N) {
    __shared__ float t[32][33];
    int n0 = blockIdx.x * 32, k0 = blockIdx.y * 32;
    int c = threadIdx.x & 31, r = threadIdx.x >> 5;   // r: 0..7
    for (int i = 0; i < 4; i++)
        t[r + i * 8][c] = W[(size_t)(k0 + r + i * 8) * N + n0 + c];
    __syncthreads();
    for (int i = 0; i < 4; i++)
        Wt[(size_t)(n0 + r + i * 8) * K + k0 + c] = f2bf(t[c][r + i * 8]);
}

// ---- transpose 512x512 W -> STACKED hi/lo bf16: q/k interleaved per 256-chunk ----
__global__ __launch_bounds__(256) void transpose_split_stk_kernel(
    const float* __restrict__ W, unsigned short* __restrict__ WtH,
    unsigned short* __restrict__ WtL, int which) {
    __shared__ float t[32][33];
    int n0 = blockIdx.x * 32, k0 = blockIdx.y * 32;
    int c = threadIdx.x & 31, r = threadIdx.x >> 5;
    for (int i = 0; i < 4; i++)
        t[r + i * 8][c] = W[(size_t)(k0 + r + i * 8) * DMODEL + n0 + c];
    __syncthreads();
    for (int i = 0; i < 4; i++) {
        int n = n0 + r + i * 8;
        int row = (n & 255) + ((n >> 8) * 512) + which * 256;
        float v = t[c][r + i * 8];
        unsigned short h = f2bf(v);
        size_t o = (size_t)row * DMODEL + k0 + c;
        WtH[o] = h;
        WtL[o] = f2bf(v - bf2f(h));
    }
}

// ---------------- stacked bias ----------------
__global__ void stack_bias_kernel(const float* __restrict__ bq,
                                  const float* __restrict__ bk, float* __restrict__ bstk) {
    int i = blockIdx.x * 256 + threadIdx.x;     // 0..1023
    if (i >= 1024) return;
    int c = i >> 9, j = i & 511;
    bstk[i] = (j < 256) ? bq[c * 256 + j] : bk[c * 256 + (j - 256)];
}

// ---------------- Wvo = Wv @ Wo (fp32, per layer; 512 blocks) ----------------
__global__ __launch_bounds__(256) void wvo_kernel(
    const float* __restrict__ Wv, const float* __restrict__ Wo,
    float* __restrict__ Wvo) {
    __shared__ float row[DMODEL];
    int k = blockIdx.x;
    int tid = threadIdx.x;
    for (int j = tid; j < DMODEL; j += 256) row[j] = Wv[(size_t)k * DMODEL + j];
    __syncthreads();
    float a0 = 0.f, a1 = 0.f;
    for (int j = 0; j < DMODEL; j++) {
        float wv = row[j];
        a0 += wv * Wo[(size_t)j * DMODEL + tid];
        a1 += wv * Wo[(size_t)j * DMODEL + tid + 256];
    }
    Wvo[(size_t)k * DMODEL + tid] = a0;
    Wvo[(size_t)k * DMODEL + tid + 256] = a1;
}

// ---------------- cb = bv @ Wo + bo ----------------
__global__ void cbias_kernel(const float* __restrict__ bv, const float* __restrict__ Wo,
                             const float* __restrict__ bo, float* __restrict__ cb) {
    int n = blockIdx.x * 256 + threadIdx.x;
    if (n >= DMODEL) return;
    float acc = bo[n];
    for (int j = 0; j < DMODEL; j++) acc += bv[j] * Wo[(size_t)j * DMODEL + n];
    cb[n] = acc;
}

// ---------------- bf16 MFMA GEMM (register staging + XCD swizzle) ------------
// 1-D grid of gridM*gridN blocks; gridN passed in. res/Cout may alias same-index.
#define BK 32
__global__ __launch_bounds__(256) void gemm_mfma_kernel(
    const unsigned short* __restrict__ A, const unsigned short* __restrict__ Wt,
    const float* __restrict__ bias, const float* res,
    void* Cout, int M, int N, int K, int act, int outMode, int gridN)
{
    __shared__ unsigned short As[128 * 40];
    __shared__ unsigned short Bs[128 * 40];
    int tid = threadIdx.x;
    int wave = tid >> 6, lane = tid & 63;
    int wm = wave & 1, wn = wave >> 1;
    int gblk, nblk;
    xcd_map(blockIdx.x, gridN, gblk, nblk);
    int bm = gblk * 128, bn = nblk * 128;

    int r0 = tid >> 2;              // 0..63
    int koff = (tid & 3) * 8;       // 0,8,16,24
    const unsigned short* Ag = A  + (size_t)(bm + r0) * K + koff;
    const unsigned short* Bg = Wt + (size_t)(bn + r0) * K + koff;

    f32x4 acc[4][4] = {};
    int frow = lane & 15, fk = (lane >> 4) * 8;

    for (int k0 = 0; k0 < K; k0 += BK) {
        bf16x8 a0 = *(const bf16x8*)(Ag + k0);
        bf16x8 a1 = *(const bf16x8*)(Ag + (size_t)64 * K + k0);
        bf16x8 b0 = *(const bf16x8*)(Bg + k0);
        bf16x8 b1 = *(const bf16x8*)(Bg + (size_t)64 * K + k0);
        __syncthreads();
        *(bf16x8*)&As[r0 * 40 + koff]        = a0;
        *(bf16x8*)&As[(r0 + 64) * 40 + koff] = a1;
        *(bf16x8*)&Bs[r0 * 40 + koff]        = b0;
        *(bf16x8*)&Bs[(r0 + 64) * 40 + koff] = b1;
        __syncthreads();
        bf16x8 af[4], bfv[4];
#pragma unroll
        for (int mi = 0; mi < 4; mi++)
            af[mi] = *(const bf16x8*)&As[(wm * 64 + mi * 16 + frow) * 40 + fk];
#pragma unroll
        for (int nj = 0; nj < 4; nj++)
            bfv[nj] = *(const bf16x8*)&Bs[(wn * 64 + nj * 16 + frow) * 40 + fk];
#pragma unroll
        for (int mi = 0; mi < 4; mi++)
#pragma unroll
            for (int nj = 0; nj < 4; nj++)
                acc[mi][nj] = __builtin_amdgcn_mfma_f32_16x16x32_bf16(
                    af[mi], bfv[nj], acc[mi][nj], 0, 0, 0);
    }

    int lrow = (lane >> 4) * 4, lcol = lane & 15;
#pragma unroll
    for (int mi = 0; mi < 4; mi++) {
        int row0 = bm + wm * 64 + mi * 16 + lrow;
#pragma unroll
        for (int nj = 0; nj < 4; nj++) {
            int col = bn + wn * 64 + nj * 16 + lcol;
            float bv = bias ? bias[col] : 0.f;
            f32x4 v = acc[mi][nj];
#pragma unroll
            for (int r = 0; r < 4; r++) {
                int row = row0 + r;
                float x = v[r] + bv;
                if (res) x += res[(size_t)row * N + col];
                if (act == 1) x = gelu_f(x);
                if (outMode == 0) ((float*)Cout)[(size_t)row * N + col] = x;
                else              ((unsigned short*)Cout)[(size_t)row * N + col] = f2bf(x);
            }
        }
    }
}

// ---------------- split-precision MFMA GEMM for q/k (fp32, XCD swizzle) -------
// Output fp32 TRANSPOSED: Ct[col*M + row]. N=512 stacked covers q&k. gridN=4.
__global__ __launch_bounds__(256) void gemm_qk_split_kernel(
    const unsigned short* __restrict__ Ahi, const unsigned short* __restrict__ Alo,
    const unsigned short* __restrict__ Whi, const unsigned short* __restrict__ Wlo,
    const float* __restrict__ bias, float* __restrict__ Ct, int M, int K, int gridN)
{
    __shared__ unsigned short AsH[128 * 40];
    __shared__ unsigned short AsL[128 * 40];
    __shared__ unsigned short BsH[128 * 40];
    __shared__ unsigned short BsL[128 * 40];
    int tid = threadIdx.x;
    int wave = tid >> 6, lane = tid & 63;
    int wm = wave & 1, wn = wave >> 1;
    int gblk, nblk;
    xcd_map(blockIdx.x, gridN, gblk, nblk);
    int bm = gblk * 128, bn = nblk * 128;

    int r0 = tid >> 2;
    int koff = (tid & 3) * 8;
    const unsigned short* AgH = Ahi + (size_t)(bm + r0) * K + koff;
    const unsigned short* AgL = Alo + (size_t)(bm + r0) * K + koff;
    const unsigned short* BgH = Whi + (size_t)(bn + r0) * K + koff;
    const unsigned short* BgL = Wlo + (size_t)(bn + r0) * K + koff;

    f32x4 acc[4][4] = {};
    int frow = lane & 15, fk = (lane >> 4) * 8;

    for (int k0 = 0; k0 < K; k0 += BK) {
        bf16x8 ah0 = *(const bf16x8*)(AgH + k0);
        bf16x8 ah1 = *(const bf16x8*)(AgH + (size_t)64 * K + k0);
        bf16x8 al0 = *(const bf16x8*)(AgL + k0);
        bf16x8 al1 = *(const bf16x8*)(AgL + (size_t)64 * K + k0);
        bf16x8 bh0 = *(const bf16x8*)(BgH + k0);
        bf16x8 bh1 = *(const bf16x8*)(BgH + (size_t)64 * K + k0);
        bf16x8 bl0 = *(const bf16x8*)(BgL + k0);
        bf16x8 bl1 = *(const bf16x8*)(BgL + (size_t)64 * K + k0);
        __syncthreads();
        *(bf16x8*)&AsH[r0 * 40 + koff]        = ah0;
        *(bf16x8*)&AsH[(r0 + 64) * 40 + koff] = ah1;
        *(bf16x8*)&AsL[r0 * 40 + koff]        = al0;
        *(bf16x8*)&AsL[(r0 + 64) * 40 + koff] = al1;
        *(bf16x8*)&BsH[r0 * 40 + koff]        = bh0;
        *(bf16x8*)&BsH[(r0 + 64) * 40 + koff] = bh1;
        *(bf16x8*)&BsL[r0 * 40 + koff]        = bl0;
        *(bf16x8*)&BsL[(r0 + 64) * 40 + koff] = bl1;
        __syncthreads();
        bf16x8 afh[4], afl[4], bfh[4], bfl[4];
#pragma unroll
        for (int mi = 0; mi < 4; mi++) {
            int o = (wm * 64 + mi * 16 + frow) * 40 + fk;
            afh[mi] = *(const bf16x8*)&AsH[o];
            afl[mi] = *(const bf16x8*)&AsL[o];
        }
#pragma unroll
        for (int nj = 0; nj < 4; nj++) {
            int o = (wn * 64 + nj * 16 + frow) * 40 + fk;
            bfh[nj] = *(const bf16x8*)&BsH[o];
            bfl[nj] = *(const bf16x8*)&BsL[o];
        }
#pragma unroll
        for (int mi = 0; mi < 4; mi++)
#pragma unroll
            for (int nj = 0; nj < 4; nj++) {
                acc[mi][nj] = __builtin_amdgcn_mfma_f32_16x16x32_bf16(
                    afh[mi], bfh[nj], acc[mi][nj], 0, 0, 0);
                acc[mi][nj] = __builtin_amdgcn_mfma_f32_16x16x32_bf16(
                    afh[mi], bfl[nj], acc[mi][nj], 0, 0, 0);
                acc[mi][nj] = __builtin_amdgcn_mfma_f32_16x16x32_bf16(
                    afl[mi], bfh[nj], acc[mi][nj], 0, 0, 0);
            }
    }

    int lrow = (lane >> 4) * 4, lcol = lane & 15;
#pragma unroll
    for (int mi = 0; mi < 4; mi++) {
        int row0 = bm + wm * 64 + mi * 16 + lrow;
#pragma unroll
        for (int nj = 0; nj < 4; nj++) {
            int col = bn + wn * 64 + nj * 16 + lcol;
            float bv = bias ? bias[col] : 0.f;
            f32x4 v = acc[mi][nj];
#pragma unroll
            for (int r = 0; r < 4; r++)
                Ct[(size_t)col * M + row0 + r] = v[r] + bv;
        }
    }
}

// ---------------- 2560-pt FFT (radix-5 + sincos twiddle + 9x radix-2 Stockham) --
template<int NT>
__device__ void fft2560(float2* bufA, float2* bufB, const float2* w512, int tid) {
    const float w5r[5] = { 1.f,  0.30901699437494742f, -0.80901699437494742f,
                          -0.80901699437494742f,  0.30901699437494742f };
    const float w5i[5] = { 0.f, -0.95105651629515357f, -0.58778525229247312f,
                           0.58778525229247312f,  0.95105651629515357f };
    __syncthreads();
    const float TWO_PI = 6.283185307179586f;
    for (int j = tid; j < SEQ; j += NT) {
        int k1 = j >> 9, n2 = j & 511;
        float ar = 0.f, ai = 0.f;
        for (int n1 = 0; n1 < 5; n1++) {
            int m = (n1 * k1) % 5;
            float2 x = bufA[n1 * 512 + n2];
            ar += x.x * w5r[m] - x.y * w5i[m];
            ai += x.x * w5i[m] + x.y * w5r[m];
        }
        float ang = -TWO_PI * (float)(n2 * k1) / 2560.0f;
        float sn, cs;
        sincosf(ang, &sn, &cs);
        bufB[j] = make_float2(ar * cs - ai * sn, ar * sn + ai * cs);
    }
    __syncthreads();
    float2* X = bufB;
    float2* Y = bufA;
    int n = 512, logs = 0;
    for (int st = 0; st < 9; st++) {
        int m = n >> 1;
        int s = 1 << logs;
        for (int t = tid; t < 1280; t += NT) {
            int sub = t >> 8;
            int r = t & 255;
            int p = r >> logs;
            int q = r & (s - 1);
            int base = sub << 9;
            float2 a = X[base + q + s * p];
            float2 b = X[base + q + s * (p + m)];
            float2 sum = make_float2(a.x + b.x, a.y + b.y);
            float2 dif = make_float2(a.x - b.x, a.y - b.y);
            float2 w = w512[p << logs];
            Y[base + q + s * (2 * p)]     = sum;
            Y[base + q + s * (2 * p + 1)] = make_float2(dif.x * w.x - dif.y * w.y,
                                                        dif.x * w.y + dif.y * w.x);
        }
        __syncthreads();
        float2* tmp = X; X = Y; Y = tmp;
        n >>= 1; logs++;
    }
    // result in bufA: bufA[k1*512 + k2] = DFT[k1 + 5*k2]
}

// one workgroup (512 threads) per (DGRP-channel group, b)
__global__ __launch_bounds__(FFT_NT) void fft_fwd_kernel(
    const float* __restrict__ qt, const float* __restrict__ kt, float* __restrict__ Z)
{
    __shared__ float2 bufA[SEQ];
    __shared__ float2 bufB[SEQ];
    __shared__ float2 w512[256];
    int d0 = blockIdx.x * DGRP;
    int b = blockIdx.y;
    int tid = threadIdx.x;
    if (tid < 256) {
        float sn, cs;
        sincosf(-6.283185307179586f * (float)tid / 512.0f, &sn, &cs);
        w512[tid] = make_float2(cs, sn);
    }
    float accR[5], accI[5];
#pragma unroll
    for (int j = 0; j < 5; j++) { accR[j] = 0.f; accI[j] = 0.f; }

    for (int col = 0; col < DGRP; col++) {
        const float* qcol = qt + (size_t)(d0 + col) * MROWS + (size_t)b * SEQ;
        const float* kcol = kt + (size_t)(d0 + col) * MROWS + (size_t)b * SEQ;
        __syncthreads();    // previous epilogue finished reading bufA
        for (int i = tid; i < SEQ; i += FFT_NT)
            bufA[i] = make_float2(qcol[i], kcol[i]);
        fft2560<FFT_NT>(bufA, bufB, w512, tid);   // entry barrier publishes writes
#pragma unroll
        for (int j = 0; j < 5; j++) {
            int f = tid + FFT_NT * j;
            int fpos = (f % 5) * 512 + (f / 5);
            int g = f ? (SEQ - f) : 0;
            int gpos = (g % 5) * 512 + (g / 5);
            float2 Z1 = bufA[fpos], Z2 = bufA[gpos];
            accR[j] += 0.5f * (Z1.x * Z2.y + Z1.y * Z2.x);            // Im(Z1*Z2)/2
            accI[j] += 0.25f * ((Z1.x * Z1.x + Z1.y * Z1.y)
                              - (Z2.x * Z2.x + Z2.y * Z2.y));         // (|Z1|^2-|Z2|^2)/4
        }
    }
#pragma unroll
    for (int j = 0; j < 5; j++) {
        int f = tid + FFT_NT * j;
        int fpos = (f % 5) * 512 + (f / 5);
        atomicAdd(&Z[((size_t)b * SEQ + fpos) * 2 + 0], accR[j]);
        atomicAdd(&Z[((size_t)b * SEQ + fpos) * 2 + 1], accI[j]);
    }
}

__global__ __launch_bounds__(FFT_NT) void fft_inv_kernel(
    const float* __restrict__ Z, float* __restrict__ mc)
{
    __shared__ float2 bufA[SEQ];
    __shared__ float2 bufB[SEQ];
    __shared__ float2 w512[256];
    int b = blockIdx.x;
    int tid = threadIdx.x;
    if (tid < 256) {
        float sn, cs;
        sincosf(-6.283185307179586f * (float)tid / 512.0f, &sn, &cs);
        w512[tid] = make_float2(cs, sn);
    }
    for (int i = tid; i < SEQ; i += FFT_NT) {
        int k1 = i % 5, k2 = i / 5;
        float zr = Z[((size_t)b * SEQ + k1 * 512 + k2) * 2 + 0];
        float zi = Z[((size_t)b * SEQ + k1 * 512 + k2) * 2 + 1];
        bufA[i] = make_float2(zr, -zi);
    }
    fft2560<FFT_NT>(bufA, bufB, w512, tid);
    const float scale = 1.0f / (2560.0f * 512.0f);
    for (int j = tid; j < SEQ; j += FFT_NT) {
        int k1 = j >> 9, k2 = j & 511;
        mc[(size_t)b * SEQ + k1 + 5 * k2] = bufA[j].x * scale;
    }
}

// ---------------- top-7 + softmax per batch ----------------
__global__ __launch_bounds__(256) void topk_kernel(
    const float* __restrict__ mc, float* __restrict__ wts, int* __restrict__ dels)
{
    __shared__ float cv[SEQ];
    __shared__ float rv[256];
    __shared__ int   ri[256];
    __shared__ float topv[TOPK];
    __shared__ int   topi[TOPK];
    int b = blockIdx.x, tid = threadIdx.x;
    for (int i = tid; i < SEQ; i += 256) cv[i] = mc[(size_t)b * SEQ + i];
    __syncthreads();
    for (int it = 0; it < TOPK; it++) {
        float bv = -2e30f; int bi = 1 << 30;
        for (int i = tid; i < SEQ; i += 256) {
            float v = cv[i];
            if (v > bv || (v == bv && i < bi)) { bv = v; bi = i; }
        }
        rv[tid] = bv; ri[tid] = bi;
        __syncthreads();
        for (int off = 128; off > 0; off >>= 1) {
            if (tid < off) {
                float v2 = rv[tid + off]; int i2 = ri[tid + off];
                if (v2 > rv[tid] || (v2 == rv[tid] && i2 < ri[tid])) {
                    rv[tid] = v2; ri[tid] = i2;
                }
            }
            __syncthreads();
        }
        if (tid == 0) { topv[it] = rv[0]; topi[it] = ri[0]; cv[ri[0]] = -1e30f; }
        __syncthreads();
    }
    if (tid == 0) {
        float mx = topv[0];
        float e[TOPK], ssum = 0.f;
        for (int i = 0; i < TOPK; i++) { e[i] = expf(topv[i] - mx); ssum += e[i]; }
        for (int i = 0; i < TOPK; i++) {
            wts[b * TOPK + i] = e[i] / ssum;
            dels[b * TOPK + i] = topi[i];
        }
    }
}

// ---------------- fused delay aggregation + bias + residual ------------------
__global__ void agg_res_kernel(const float* __restrict__ u, const float* __restrict__ x,
                               const float* __restrict__ cb,
                               const float* __restrict__ wts, const int* __restrict__ dels,
                               float* __restrict__ x1) {
    size_t idx = (size_t)blockIdx.x * 256 + threadIdx.x;
    if (idx >= SD) return;
    int d = idx & (DMODEL - 1);
    size_t r = idx >> 9;
    int s = (int)(r % SEQ);
    int b = (int)(r / SEQ);
    float acc = cb[d] + x[idx];
    for (int i = 0; i < TOPK; i++) {
        int del = dels[b * TOPK + i];
        float w = wts[b * TOPK + i];
        int ss = s + del; if (ss >= SEQ) ss -= SEQ;
        acc += w * u[((size_t)b * SEQ + ss) * DMODEL + d];
    }
    x1[idx] = acc;
}

// ---------------- x - moving_avg(x): running-window ----------------
#define MA_MODE_PLAIN 0
#define MA_MODE_BF    1
#define MA_MODE_SPLIT 2
template<int MODE>
__device__ __forceinline__ void ma_run_body(
    const float* __restrict__ x, float* __restrict__ out,
    unsigned short* __restrict__ o1, unsigned short* __restrict__ o2)
{
    int tid = threadIdx.x;
    int s0 = blockIdx.x * 128;
    int d  = blockIdx.y * 256 + tid;
    int b  = blockIdx.z;
    const float* xb = x + (size_t)b * SEQ * DMODEL + d;
    float sum = 0.f;
#pragma unroll
    for (int j = -12; j <= 12; j++) {
        int ss = s0 + j;
        ss = ss < 0 ? 0 : (ss > SEQ - 1 ? SEQ - 1 : ss);
        sum += xb[(size_t)ss * DMODEL];
    }
    for (int s = s0; s < s0 + 128; s++) {
        float v = xb[(size_t)s * DMODEL] - sum * (1.0f / 25.0f);
        size_t o = ((size_t)b * SEQ + s) * DMODEL + d;
        out[o] = v;
        if (MODE == MA_MODE_BF) {
            o1[o] = f2bf(v);
        } else if (MODE == MA_MODE_SPLIT) {
            unsigned short h = f2bf(v);
            o1[o] = h;
            o2[o] = f2bf(v - bf2f(h));
        }
        int add = s + 13; if (add > SEQ - 1) add = SEQ - 1;
        int sub = s - 12; if (sub < 0) sub = 0;
        sum += xb[(size_t)add * DMODEL] - xb[(size_t)sub * DMODEL];
    }
}
__global__ __launch_bounds__(256) void ma_sub_kernel(
    const float* __restrict__ x, float* __restrict__ out) {
    ma_run_body<MA_MODE_PLAIN>(x, out, nullptr, nullptr);
}
__global__ __launch_bounds__(256) void ma_sub_bf_kernel(
    const float* __restrict__ x, float* __restrict__ out,
    unsigned short* __restrict__ obf) {
    ma_run_body<MA_MODE_BF>(x, out, obf, nullptr);
}
__global__ __launch_bounds__(256) void ma_sub_split_kernel(
    const float* __restrict__ x, float* __restrict__ out,
    unsigned short* __restrict__ hi, unsigned short* __restrict__ lo) {
    ma_run_body<MA_MODE_SPLIT>(x, out, hi, lo);
}

// ---------------- layernorm over last dim ----------------
__global__ __launch_bounds__(256) void ln_kernel(
    const float* __restrict__ x, const float* __restrict__ g,
    const float* __restrict__ be, float* __restrict__ xh)
{
    int row = blockIdx.x;
    int tid = threadIdx.x;
    __shared__ float red[256];
    const float* xr = x + (size_t)row * DMODEL;
    float v0 = xr[tid], v1 = xr[tid + 256];
    red[tid] = v0 + v1;
    __syncthreads();
    for (int off = 128; off > 0; off >>= 1) {
        if (tid < off) red[tid] += red[tid + off];
        __syncthreads();
    }
    float mu = red[0] / (float)DMODEL;
    __syncthreads();
    float d0 = v0 - mu, d1 = v1 - mu;
    red[tid] = d0 * d0 + d1 * d1;
    __syncthreads();
    for (int off = 128; off > 0; off >>= 1) {
        if (tid < off) red[tid] += red[tid + off];
        __syncthreads();
    }
    float inv = rsqrtf(red[0] / (float)DMODEL + 1e-5f);
    xh[(size_t)row * DMODEL + tid]       = d0 * inv * g[tid] + be[tid];
    xh[(size_t)row * DMODEL + tid + 256] = d1 * inv * g[tid + 256] + be[tid + 256];
}

// ---------------- per-(b,d) mean over sequence (parallel, atomic partials) ----
__global__ __launch_bounds__(256) void colmean_kernel(
    const float* __restrict__ xh, float* __restrict__ cm) {
    int idx = blockIdx.x * 256 + threadIdx.x;   // (b,d) 0..8191
    int d = idx & (DMODEL - 1), b = idx >> 9;
    int s0 = blockIdx.y * 128;
    float acc = 0.f;
    for (int s = s0; s < s0 + 128; s++)
        acc += xh[((size_t)b * SEQ + s) * DMODEL + d];
    atomicAdd(&cm[idx], acc * (1.0f / (float)SEQ));
}

__global__ __launch_bounds__(256) void final_kernel(
    const float* __restrict__ xh, const float* __restrict__ cm,
    const float* __restrict__ Wp, const float* __restrict__ bp,
    float* __restrict__ out)
{
    int b = blockIdx.y, chunk = blockIdx.x;
    int tid = threadIdx.x;
    const size_t per = (size_t)SEQ * DMODEL / 64;
    size_t start = (size_t)chunk * per;
    float acc = 0.f;
    for (size_t i = start + tid; i < start + per; i += 256) {
        int d = (int)(i & (DMODEL - 1));
        float v = xh[(size_t)b * SEQ * DMODEL + i] - cm[b * DMODEL + d];
        acc += gelu_f(v) * Wp[i];
    }
    __shared__ float red[256];
    red[tid] = acc;
    __syncthreads();
    for (int off = 128; off > 0; off >>= 1) {
        if (tid < off) red[tid] += red[tid + off];
        __syncthreads();
    }
    if (tid == 0) {
        atomicAdd(&out[b], red[0]);
        if (chunk == 0) atomicAdd(&out[b], bp[0]);
    }
}

// ---------------- orchestration: 3-buffer rotation, NO input/output aliasing ----
extern "C" void kernel_launch(void* const* d_in, const int* in_sizes, int n_in,
                              void* d_out, int out_size, void* d_ws, size_t ws_size,
                              hipStream_t stream) {
    const float* data  = (const float*)d_in[0];
    const float* mask  = (const float*)d_in[1];
    const float* Wemb  = (const float*)d_in[2];
    const float* Wq    = (const float*)d_in[3];
    const float* bq    = (const float*)d_in[4];
    const float* Wk    = (const float*)d_in[5];
    const float* bk    = (const float*)d_in[6];
    const float* Wv    = (const float*)d_in[7];
    const float* bv    = (const float*)d_in[8];
    const float* Wo    = (const float*)d_in[9];
    const float* bo    = (const float*)d_in[10];
    const float* Wc1   = (const float*)d_in[11];
    const float* Wc2   = (const float*)d_in[12];
    const float* gamma = (const float*)d_in[13];
    const float* beta  = (const float*)d_in[14];
    const float* Wp    = (const float*)d_in[15];
    const float* bp    = (const float*)d_in[16];
    float* out = (float*)d_out;

    float* buf0 = (float*)d_ws;
    float* buf1 = buf0 + SD;
    float* buf2 = buf1 + SD;

    unsigned short* WstkH = (unsigned short*)(buf2 + SD);   // 2*512*512 stacked q/k hi
    unsigned short* WstkL = WstkH + 2 * DMODEL * DMODEL;    // stacked q/k lo
    unsigned short* Wvot  = WstkL + 2 * DMODEL * DMODEL;    // bf16 [N][K] of Wv@Wo
    unsigned short* Wc1t  = Wvot + DMODEL * DMODEL;         // [2048][512]
    unsigned short* Wc2t  = Wc1t + (size_t)DMODEL * DFF;    // [512][2048]
    float* WvoF = (float*)(Wc2t + (size_t)DMODEL * DFF);    // fp32 Wv@Wo (512x512)
    float* CB   = WvoF + (size_t)DMODEL * DMODEL;           // cb = bv@Wo + bo
    float* Bstk = CB + DMODEL;                              // stacked q/k bias (1024)
    float* Zb = Bstk + 1024;
    float* MC = Zb + (size_t)BATCH * SEQ * 2;
    float* WT = MC + (size_t)BATCH * SEQ;
    int*   DL = (int*)(WT + BATCH * TOPK);
    float* CM = (float*)(DL + BATCH * TOPK);

    const int NB  = (int)((SD + 255) / 256);
    const int NB4 = (int)((SD / 4 + 255) / 256);
    dim3 gMA(SEQ / 128, 2, BATCH);              // (20, 2, 16) running-window MA

    float* X  = buf0;   // x fp32
    float* HL = buf1;   // hi/lo pool
    float* S  = buf2;   // scratch

    embed_kernel<<<NB, 256, 0, stream>>>(data, mask, Wemb, X);
    conv_split_kernel<<<NB4, 256, 0, stream>>>(
        X, (unsigned short*)HL + SD, (unsigned short*)HL, SD);  // hi -> upper, lo -> lower

    // 1-D swizzled GEMM grids: blocks = gridM*gridN (gridM % 8 == 0)
    const int gSqBlocks = (MROWS / 128) * (DMODEL / 128);       // 320*4 = 1280
    const int gF1Blocks = (FFN_CHUNK / 128) * (DFF / 128);      // 160*16 = 2560
    const int gF2Blocks = (FFN_CHUNK / 128) * (DMODEL / 128);   // 160*4 = 640

    for (int l = 0; l < NLAYERS; l++) {
        const float* wq = Wq + (size_t)l * DMODEL * DMODEL;
        const float* wk = Wk + (size_t)l * DMODEL * DMODEL;
        const float* wv = Wv + (size_t)l * DMODEL * DMODEL;
        const float* wo = Wo + (size_t)l * DMODEL * DMODEL;
        const float* bqL = bq + (size_t)l * DMODEL;
        const float* bkL = bk + (size_t)l * DMODEL;
        const float* bvL = bv + (size_t)l * DMODEL;
        const float* boL = bo + (size_t)l * DMODEL;
        const float* wc1 = Wc1 + (size_t)l * DMODEL * DFF;
        const float* wc2 = Wc2 + (size_t)l * DFF * DMODEL;

        unsigned short* Lbf = (unsigned short*)HL;      // x_lo (lower half)
        unsigned short* Hbf = Lbf + SD;                 // x_hi (upper half)
        float* qtf = S;                                 // q cols (MROWS*256)
        float* ktf = S + (size_t)MROWS * CHUNK_D;       // k cols

        dim3 gT(DMODEL / 32, DMODEL / 32);
        transpose_split_stk_kernel<<<gT, 256, 0, stream>>>(wq, WstkH, WstkL, 0);
        transpose_split_stk_kernel<<<gT, 256, 0, stream>>>(wk, WstkH, WstkL, 1);
        stack_bias_kernel<<<4, 256, 0, stream>>>(bqL, bkL, Bstk);
        wvo_kernel<<<DMODEL, 256, 0, stream>>>(wv, wo, WvoF);
        transpose_bf16_kernel<<<gT, 256, 0, stream>>>(WvoF, Wvot, DMODEL, DMODEL);
        cbias_kernel<<<2, 256, 0, stream>>>(bvL, wo, boL, CB);
        transpose_bf16_kernel<<<dim3(DFF / 32, DMODEL / 32), 256, 0, stream>>>(wc1, Wc1t, DMODEL, DFF);
        transpose_bf16_kernel<<<dim3(DMODEL / 32, DFF / 32), 256, 0, stream>>>(wc2, Wc2t, DFF, DMODEL);

        // q&k stacked: one split GEMM per 256-col chunk into S (N=512 covers both)
        hipMemsetAsync(Zb, 0, (size_t)BATCH * SEQ * 2 * sizeof(float), stream);
        for (int c = 0; c < DMODEL / CHUNK_D; c++) {
            gemm_qk_split_kernel<<<gSqBlocks, 256, 0, stream>>>(
                Hbf, Lbf, WstkH + (size_t)c * 512 * DMODEL,
                WstkL + (size_t)c * 512 * DMODEL, Bstk + c * 512,
                S, MROWS, DMODEL, DMODEL / 128);
            fft_fwd_kernel<<<dim3(CHUNK_D / DGRP, BATCH), FFT_NT, 0, stream>>>(qtf, ktf, Zb);
        }
        fft_inv_kernel<<<BATCH, FFT_NT, 0, stream>>>(Zb, MC);
        topk_kernel<<<BATCH, 256, 0, stream>>>(MC, WT, DL);

        // u = x@(Wv@Wo) -> S fp32 (qtf/ktf dead)
        gemm_mfma_kernel<<<gSqBlocks, 256, 0, stream>>>(Hbf, Wvot, nullptr, nullptr, S,
                                                        MROWS, DMODEL, DMODEL, 0, 0,
                                                        DMODEL / 128);
        // x1 = sum w_i roll(u) + cb + x -> HL as fp32 (x hi/lo dead)
        agg_res_kernel<<<NB, 256, 0, stream>>>(S, X, CB, WT, DL, HL);
        // x2 = x1 - MA(x1): fp32 -> X (x dead), bf16 -> S (u dead). No aliasing.
        ma_sub_bf_kernel<<<gMA, 256, 0, stream>>>(HL, X, (unsigned short*)S);
        // FFN in 2 row-chunks: gelu bf16 fills HL exactly (x1 dead);
        // z in-place over X (res==out, same-index).
        for (int c = 0; c < MROWS / FFN_CHUNK; c++) {
            const unsigned short* x2c = (unsigned short*)S + (size_t)c * FFN_CHUNK * DMODEL;
            float* xz = X + (size_t)c * FFN_CHUNK * DMODEL;
            gemm_mfma_kernel<<<gF1Blocks, 256, 0, stream>>>(x2c, Wc1t, nullptr, nullptr,
                                                            (unsigned short*)HL,
                                                            FFN_CHUNK, DFF, DMODEL, 1, 1,
                                                            DFF / 128);
            gemm_mfma_kernel<<<gF2Blocks, 256, 0, stream>>>((unsigned short*)HL, Wc2t,
                                                            nullptr, xz, xz,
                                                            FFN_CHUNK, DMODEL, DFF, 0, 0,
                                                            DMODEL / 128);
        }
        // h = z - MA(z): z in X -> h fp32 -> S (+ hi/lo -> HL if another layer)
        if (l + 1 < NLAYERS)
            ma_sub_split_kernel<<<gMA, 256, 0, stream>>>(
                X, S, (unsigned short*)HL + SD, (unsigned short*)HL);
        else
            ma_sub_kernel<<<gMA, 256, 0, stream>>>(X, S);
        // rotate: next layer's x is in S
        float* tmp = X; X = S; S = tmp;
    }

    // final h is in X; use HL for xh
    ln_kernel<<<MROWS, 256, 0, stream>>>(X, gamma, beta, HL);
    hipMemsetAsync(CM, 0, (size_t)BATCH * DMODEL * sizeof(float), stream);
    colmean_kernel<<<dim3(32, 20), 256, 0, stream>>>(HL, CM);
    hipMemsetAsync(out, 0, (size_t)out_size * sizeof(float), stream);
    final_kernel<<<dim3(64, BATCH), 256, 0, stream>>>(HL, CM, Wp, bp, out);
}